// Round 1
// baseline (9793.787 us; speedup 1.0000x reference)
//
#include <hip/hip_runtime.h>
#include <math.h>

#define N_ 32
#define S_ 197
#define D_ 768
#define H_ 12
#define DH_ 64
#define L_ 8
#define FF_ 3072
#define OUT_ 1000
#define MTOK (N_ * S_)      // 6304
#define ND (N_ * S_ * D_)   // 4841472

__device__ __forceinline__ float wred_max(float v) {
#pragma unroll
  for (int m = 32; m > 0; m >>= 1) v = fmaxf(v, __shfl_xor(v, m, 64));
  return v;
}
__device__ __forceinline__ float wred_sum(float v) {
#pragma unroll
  for (int m = 32; m > 0; m >>= 1) v += __shfl_xor(v, m, 64);
  return v;
}

// ---------------- patchify: images (N,C,224,224) -> patches (6272, 768) ----------------
__global__ __launch_bounds__(256) void patchify_kernel(const float* __restrict__ img,
                                                       float* __restrict__ patches) {
  int idx = blockIdx.x * 256 + threadIdx.x;
  if (idx >= 6272 * 768) return;
  int mp = idx / 768, kk = idx - mp * 768;
  int n = mp / 196, p = mp - n * 196;
  int py = p / 14, px = p - py * 14;
  int c = kk >> 8, r = kk & 255;
  int u = r >> 4, vv = r & 15;
  patches[idx] = img[((size_t)(n * 3 + c) * 224 + py * 16 + u) * 224 + px * 16 + vv];
}

// x[n,0,:] = cls + pos[0]
__global__ __launch_bounds__(256) void cls_init_kernel(const float* __restrict__ cls_tok,
                                                       const float* __restrict__ pos,
                                                       float* __restrict__ x) {
  int idx = blockIdx.x * 256 + threadIdx.x;  // 32*768
  int n = idx / 768, d = idx - n * 768;
  x[(size_t)n * S_ * D_ + d] = cls_tok[d] + pos[d];
}

// ---------------- generic 128x128x16 fp32 GEMM, 8x8 micro-tile ----------------
#define EPI_PATCH 1
#define EPI_GELU 2
#define EPI_RES 3

template <int EPI>
__global__ __launch_bounds__(256) void gemm128(const float* __restrict__ A,
                                               const float* __restrict__ B,
                                               const float* __restrict__ bias,
                                               float* __restrict__ C, int M, int K, int Nc,
                                               const float* __restrict__ pos) {
  __shared__ float As[16 * 132];  // [k][m] transposed, padded
  __shared__ float Bs[16 * 132];  // [k][n], padded
  int tid = threadIdx.x;
  int tx = tid & 15, ty = tid >> 4;
  int n0 = blockIdx.x * 128, m0 = blockIdx.y * 128;
  float acc[8][8];
#pragma unroll
  for (int i = 0; i < 8; ++i)
#pragma unroll
    for (int j = 0; j < 8; ++j) acc[i][j] = 0.f;

  for (int k0 = 0; k0 < K; k0 += 16) {
#pragma unroll
    for (int it = 0; it < 2; ++it) {
      int f4 = it * 256 + tid;
      // A: 128 rows x 16 cols
      int row = f4 >> 2, c4 = f4 & 3;
      int gr = m0 + row;
      if (gr > M - 1) gr = M - 1;
      float4 av = *(const float4*)&A[(size_t)gr * K + k0 + c4 * 4];
      As[(c4 * 4 + 0) * 132 + row] = av.x;
      As[(c4 * 4 + 1) * 132 + row] = av.y;
      As[(c4 * 4 + 2) * 132 + row] = av.z;
      As[(c4 * 4 + 3) * 132 + row] = av.w;
      // B: 16 rows x 128 cols
      int brow = f4 >> 5, bc4 = f4 & 31;
      float4 bv = *(const float4*)&B[(size_t)(k0 + brow) * Nc + n0 + bc4 * 4];
      *(float4*)&Bs[brow * 132 + bc4 * 4] = bv;
    }
    __syncthreads();
#pragma unroll
    for (int kk = 0; kk < 16; ++kk) {
      float4 a0 = *(const float4*)&As[kk * 132 + ty * 8];
      float4 a1 = *(const float4*)&As[kk * 132 + ty * 8 + 4];
      float4 b0 = *(const float4*)&Bs[kk * 132 + tx * 8];
      float4 b1 = *(const float4*)&Bs[kk * 132 + tx * 8 + 4];
      float a[8] = {a0.x, a0.y, a0.z, a0.w, a1.x, a1.y, a1.z, a1.w};
      float b[8] = {b0.x, b0.y, b0.z, b0.w, b1.x, b1.y, b1.z, b1.w};
#pragma unroll
      for (int i = 0; i < 8; ++i)
#pragma unroll
        for (int j = 0; j < 8; ++j) acc[i][j] += a[i] * b[j];
    }
    __syncthreads();
  }

#pragma unroll
  for (int i = 0; i < 8; ++i) {
    int grow = m0 + ty * 8 + i;
    if (grow >= M) break;
    if (EPI == EPI_PATCH) {
      int n = grow / 196, t = grow - n * 196 + 1;
      float* cp = &C[((size_t)n * S_ + t) * 768];
      const float* pp = &pos[(size_t)t * 768];
#pragma unroll
      for (int j = 0; j < 8; ++j) {
        int col = n0 + tx * 8 + j;
        cp[col] = acc[i][j] + bias[col] + pp[col];
      }
    } else if (EPI == EPI_GELU) {
#pragma unroll
      for (int j = 0; j < 8; ++j) {
        int col = n0 + tx * 8 + j;
        float v = acc[i][j] + bias[col];
        C[(size_t)grow * FF_ + col] = 0.5f * v * (1.f + erff(v * 0.70710678118654752f));
      }
    } else {  // EPI_RES: C += A@B + bias
#pragma unroll
      for (int j = 0; j < 8; ++j) {
        int col = n0 + tx * 8 + j;
        C[(size_t)grow * 768 + col] += acc[i][j] + bias[col];
      }
    }
  }
}

// ---------------- LayerNorm: one wave per token ----------------
__global__ __launch_bounds__(256) void ln_kernel(const float* __restrict__ x,
                                                 float* __restrict__ out,
                                                 const float* __restrict__ w,
                                                 const float* __restrict__ b) {
  int tok = blockIdx.x * 4 + (threadIdx.x >> 6);
  int lane = threadIdx.x & 63;
  const float* xr = x + (size_t)tok * 768;
  float4 v[3];
  float s = 0.f, s2 = 0.f;
#pragma unroll
  for (int i = 0; i < 3; ++i) {
    v[i] = *(const float4*)&xr[i * 256 + lane * 4];
    s += v[i].x + v[i].y + v[i].z + v[i].w;
    s2 += v[i].x * v[i].x + v[i].y * v[i].y + v[i].z * v[i].z + v[i].w * v[i].w;
  }
  s = wred_sum(s);
  s2 = wred_sum(s2);
  float mu = s * (1.f / 768.f);
  float var = s2 * (1.f / 768.f) - mu * mu;
  float rs = rsqrtf(var + 1e-5f);
  float* orow = out + (size_t)tok * 768;
#pragma unroll
  for (int i = 0; i < 3; ++i) {
    float4 wv = *(const float4*)&w[i * 256 + lane * 4];
    float4 bv = *(const float4*)&b[i * 256 + lane * 4];
    float4 ov;
    ov.x = (v[i].x - mu) * rs * wv.x + bv.x;
    ov.y = (v[i].y - mu) * rs * wv.y + bv.y;
    ov.z = (v[i].z - mu) * rs * wv.z + bv.z;
    ov.w = (v[i].w - mu) * rs * wv.w + bv.w;
    *(float4*)&orow[i * 256 + lane * 4] = ov;
  }
}

// ---------------- QKV projection: per-head 64x64, block = 64 tokens x 1 head ----------------
__global__ __launch_bounds__(256) void qkv_kernel(
    const float* __restrict__ h, const float* __restrict__ Wq, const float* __restrict__ Wk,
    const float* __restrict__ Wv, const float* __restrict__ bq, const float* __restrict__ bk,
    const float* __restrict__ bv, float* __restrict__ qo, float* __restrict__ ko,
    float* __restrict__ vo) {
  __shared__ float Hs[64 * 68];  // [d][m] transposed
  __shared__ float Ws[64 * 68];  // [d][e]
  int tid = threadIdx.x;
  int which = blockIdx.z;
  const float* W = which == 0 ? Wq : (which == 1 ? Wk : Wv);
  const float* bb = which == 0 ? bq : (which == 1 ? bk : bv);
  float* out = which == 0 ? qo : (which == 1 ? ko : vo);
  int head = blockIdx.y;
  int m0 = blockIdx.x * 64;
#pragma unroll
  for (int it = 0; it < 4; ++it) {
    int f4 = it * 256 + tid;
    int row = f4 >> 4, c4 = f4 & 15;
    int gr = m0 + row;
    if (gr > MTOK - 1) gr = MTOK - 1;
    float4 hv = *(const float4*)&h[(size_t)gr * 768 + head * 64 + c4 * 4];
    Hs[(c4 * 4 + 0) * 68 + row] = hv.x;
    Hs[(c4 * 4 + 1) * 68 + row] = hv.y;
    Hs[(c4 * 4 + 2) * 68 + row] = hv.z;
    Hs[(c4 * 4 + 3) * 68 + row] = hv.w;
    float4 wv = *(const float4*)&W[(size_t)head * 4096 + row * 64 + c4 * 4];
    *(float4*)&Ws[row * 68 + c4 * 4] = wv;
  }
  __syncthreads();
  int tx = tid & 15, ty = tid >> 4;
  float acc[4][4];
#pragma unroll
  for (int i = 0; i < 4; ++i)
#pragma unroll
    for (int j = 0; j < 4; ++j) acc[i][j] = 0.f;
#pragma unroll 4
  for (int kk = 0; kk < 64; ++kk) {
    float4 a = *(const float4*)&Hs[kk * 68 + ty * 4];
    float4 bf = *(const float4*)&Ws[kk * 68 + tx * 4];
    float av[4] = {a.x, a.y, a.z, a.w};
    float bvv[4] = {bf.x, bf.y, bf.z, bf.w};
#pragma unroll
    for (int i = 0; i < 4; ++i)
#pragma unroll
      for (int j = 0; j < 4; ++j) acc[i][j] += av[i] * bvv[j];
  }
#pragma unroll
  for (int i = 0; i < 4; ++i) {
    int grow = m0 + ty * 4 + i;
    if (grow >= MTOK) break;
#pragma unroll
    for (int j = 0; j < 4; ++j) {
      int e = tx * 4 + j;
      out[(size_t)grow * 768 + head * 64 + e] = acc[i][j] + bb[head * 64 + e];
    }
  }
}

// ---------------- fused flash attention: block = (qchunk64, head, n) ----------------
__global__ __launch_bounds__(256) void attn_kernel(const float* __restrict__ Q,
                                                   const float* __restrict__ Kb,
                                                   const float* __restrict__ Vb,
                                                   float* __restrict__ X) {
  __shared__ float Qs[64 * 68];
  __shared__ float Kt[64 * 68];
  __shared__ float Vt[64 * 68];
  __shared__ float Ps[4][8][64];
  int tid = threadIdx.x;
  int w = tid >> 6, lane = tid & 63;
  int qc = blockIdx.x, hh = blockIdx.y, n = blockIdx.z;
  int q0 = qc * 64;
  // stage Q chunk
#pragma unroll
  for (int it = 0; it < 4; ++it) {
    int f4 = it * 256 + tid;
    int row = f4 >> 4, c4 = f4 & 15;
    int gr = q0 + row;
    if (gr > S_ - 1) gr = S_ - 1;
    float4 qv = *(const float4*)&Q[((size_t)n * S_ + gr) * 768 + hh * 64 + c4 * 4];
    *(float4*)&Qs[row * 68 + c4 * 4] = qv;
  }
  float m[2][8], l[2][8], o[2][8];
#pragma unroll
  for (int g = 0; g < 2; ++g)
#pragma unroll
    for (int r = 0; r < 8; ++r) {
      m[g][r] = -INFINITY;
      l[g][r] = 0.f;
      o[g][r] = 0.f;
    }

  for (int t = 0; t < 4; ++t) {
    __syncthreads();  // Qs ready (t=0) / prior-tile consumers done
#pragma unroll
    for (int it = 0; it < 4; ++it) {
      int f4 = it * 256 + tid;
      int row = f4 >> 4, c4 = f4 & 15;
      int gk = t * 64 + row;
      if (gk > S_ - 1) gk = S_ - 1;
      size_t base = ((size_t)n * S_ + gk) * 768 + hh * 64 + c4 * 4;
      *(float4*)&Kt[row * 68 + c4 * 4] = *(const float4*)&Kb[base];
      *(float4*)&Vt[row * 68 + c4 * 4] = *(const float4*)&Vb[base];
    }
    __syncthreads();
    int jj = t * 64 + lane;
    bool valid = jj < S_;
    for (int g = 0; g < 2; ++g) {
      int rbase = w * 16 + g * 8;
      float s[8];
#pragma unroll
      for (int r = 0; r < 8; ++r) s[r] = 0.f;
#pragma unroll 4
      for (int e4 = 0; e4 < 16; ++e4) {
        float4 kv = *(const float4*)&Kt[lane * 68 + e4 * 4];
#pragma unroll
        for (int r = 0; r < 8; ++r) {
          float4 qv = *(const float4*)&Qs[(rbase + r) * 68 + e4 * 4];
          s[r] += qv.x * kv.x + qv.y * kv.y + qv.z * kv.z + qv.w * kv.w;
        }
      }
#pragma unroll
      for (int r = 0; r < 8; ++r) {
        float sv = valid ? s[r] * 0.125f : -INFINITY;
        float tm = wred_max(sv);
        float mn = fmaxf(m[g][r], tm);
        float alpha = expf(m[g][r] - mn);
        float p = expf(sv - mn);
        float psum = wred_sum(p);
        l[g][r] = l[g][r] * alpha + psum;
        o[g][r] *= alpha;
        m[g][r] = mn;
        Ps[w][r][lane] = p;
      }
      __syncthreads();
#pragma unroll 8
      for (int j = 0; j < 64; ++j) {
        float vv = Vt[j * 68 + lane];
#pragma unroll
        for (int r = 0; r < 8; ++r) o[g][r] += Ps[w][r][j] * vv;
      }
      __syncthreads();
    }
  }
#pragma unroll
  for (int g = 0; g < 2; ++g)
#pragma unroll
    for (int r = 0; r < 8; ++r) {
      int row = q0 + w * 16 + g * 8 + r;
      if (row < S_) X[((size_t)n * S_ + row) * 768 + hh * 64 + lane] += o[g][r] / l[g][r];
    }
}

// ---------------- classifier head + softmax: one block per sample ----------------
__global__ __launch_bounds__(256) void head_kernel(const float* __restrict__ x,
                                                   const float* __restrict__ Wout,
                                                   const float* __restrict__ bout,
                                                   float* __restrict__ out) {
  __shared__ float cls[768];
  __shared__ float red[4];
  int n = blockIdx.x, tid = threadIdx.x;
  int w = tid >> 6, lane = tid & 63;
  for (int d = tid; d < 768; d += 256) cls[d] = x[(size_t)n * S_ * D_ + d];
  __syncthreads();
  int j0 = tid * 4;
  bool act = j0 < 1000;
  float a0 = 0.f, a1 = 0.f, a2 = 0.f, a3 = 0.f;
  if (act) {
    for (int kk = 0; kk < 768; ++kk) {
      float c = cls[kk];
      float4 wv = *(const float4*)&Wout[(size_t)kk * 1000 + j0];
      a0 += c * wv.x;
      a1 += c * wv.y;
      a2 += c * wv.z;
      a3 += c * wv.w;
    }
    a0 += bout[j0];
    a1 += bout[j0 + 1];
    a2 += bout[j0 + 2];
    a3 += bout[j0 + 3];
  }
  float mx = act ? fmaxf(fmaxf(a0, a1), fmaxf(a2, a3)) : -INFINITY;
  mx = wred_max(mx);
  if (lane == 0) red[w] = mx;
  __syncthreads();
  mx = fmaxf(fmaxf(red[0], red[1]), fmaxf(red[2], red[3]));
  __syncthreads();
  float e0 = 0.f, e1 = 0.f, e2 = 0.f, e3 = 0.f, ss = 0.f;
  if (act) {
    e0 = expf(a0 - mx);
    e1 = expf(a1 - mx);
    e2 = expf(a2 - mx);
    e3 = expf(a3 - mx);
    ss = e0 + e1 + e2 + e3;
  }
  ss = wred_sum(ss);
  if (lane == 0) red[w] = ss;
  __syncthreads();
  ss = red[0] + red[1] + red[2] + red[3];
  if (act) {
    float inv = 1.f / ss;
    out[(size_t)n * 1000 + j0] = e0 * inv;
    out[(size_t)n * 1000 + j0 + 1] = e1 * inv;
    out[(size_t)n * 1000 + j0 + 2] = e2 * inv;
    out[(size_t)n * 1000 + j0 + 3] = e3 * inv;
  }
}

extern "C" void kernel_launch(void* const* d_in, const int* in_sizes, int n_in, void* d_out,
                              int out_size, void* d_ws, size_t ws_size, hipStream_t stream) {
  const float* images = (const float*)d_in[0];
  const float* Wm = (const float*)d_in[1];
  const float* bm = (const float*)d_in[2];
  const float* cls_tok = (const float*)d_in[3];
  const float* pos_emb = (const float*)d_in[4];
  const float* ln1_w = (const float*)d_in[5];
  const float* ln1_b = (const float*)d_in[6];
  const float* Wq = (const float*)d_in[7];
  const float* bq = (const float*)d_in[8];
  const float* Wk = (const float*)d_in[9];
  const float* bk = (const float*)d_in[10];
  const float* Wv = (const float*)d_in[11];
  const float* bv = (const float*)d_in[12];
  const float* ln2_w = (const float*)d_in[13];
  const float* ln2_b = (const float*)d_in[14];
  const float* W1 = (const float*)d_in[15];
  const float* b1 = (const float*)d_in[16];
  const float* W2 = (const float*)d_in[17];
  const float* b2 = (const float*)d_in[18];
  const float* Wout = (const float*)d_in[19];
  const float* bout = (const float*)d_in[20];
  float* out = (float*)d_out;
  float* ws = (float*)d_ws;
  float* x = ws;                               // ND floats
  float* hbuf = ws + (size_t)ND;               // ND floats
  float* scratch = ws + (size_t)2 * ND;        // max(3*ND, MTOK*FF_) floats
  float* qb = scratch;
  float* kb = scratch + (size_t)ND;
  float* vb = scratch + (size_t)2 * ND;
  float* gb = scratch;       // MLP hidden (reuses qkv space)
  float* patches = scratch;  // pre-layer (reuses qkv space)

  patchify_kernel<<<(6272 * 768 + 255) / 256, 256, 0, stream>>>(images, patches);
  gemm128<EPI_PATCH><<<dim3(6, 49), 256, 0, stream>>>(patches, Wm, bm, x, 6272, 768, 768,
                                                      pos_emb);
  cls_init_kernel<<<(32 * 768) / 256, 256, 0, stream>>>(cls_tok, pos_emb, x);

  for (int l = 0; l < 8; ++l) {
    ln_kernel<<<MTOK / 4, 256, 0, stream>>>(x, hbuf, ln1_w + l * 768, ln1_b + l * 768);
    qkv_kernel<<<dim3(99, 12, 3), 256, 0, stream>>>(
        hbuf, Wq + (size_t)l * 49152, Wk + (size_t)l * 49152, Wv + (size_t)l * 49152,
        bq + l * 768, bk + l * 768, bv + l * 768, qb, kb, vb);
    attn_kernel<<<dim3(4, 12, 32), 256, 0, stream>>>(qb, kb, vb, x);
    ln_kernel<<<MTOK / 4, 256, 0, stream>>>(x, hbuf, ln2_w + l * 768, ln2_b + l * 768);
    gemm128<EPI_GELU><<<dim3(24, 50), 256, 0, stream>>>(
        hbuf, W1 + (size_t)l * 768 * 3072, b1 + l * 3072, gb, MTOK, 768, 3072, nullptr);
    gemm128<EPI_RES><<<dim3(6, 50), 256, 0, stream>>>(
        gb, W2 + (size_t)l * 3072 * 768, b2 + l * 768, x, MTOK, 3072, 768, nullptr);
  }
  head_kernel<<<32, 256, 0, stream>>>(x, Wout, bout, out);
}

// Round 2
// 5324.235 us; speedup vs baseline: 1.8395x; 1.8395x over previous
//
#include <hip/hip_runtime.h>
#include <math.h>

#define N_ 32
#define S_ 197
#define D_ 768
#define H_ 12
#define L_ 8
#define FF_ 3072
#define MTOK (N_ * S_)      // 6304
#define ND (N_ * S_ * D_)   // 4841472

typedef __attribute__((ext_vector_type(8))) short short8x;
typedef __attribute__((ext_vector_type(4))) float floatx4;
typedef unsigned short ushort_t;
typedef unsigned int uint_t;

__device__ __forceinline__ ushort_t f2bf_rn(float x) {
  uint_t u = __float_as_uint(x);
  uint_t r = (u + 0x7fff + ((u >> 16) & 1)) >> 16;
  return (ushort_t)r;
}
__device__ __forceinline__ float bf2f(ushort_t h) {
  return __uint_as_float(((uint_t)h) << 16);
}

__device__ __forceinline__ float wred_max(float v) {
#pragma unroll
  for (int m = 32; m > 0; m >>= 1) v = fmaxf(v, __shfl_xor(v, m, 64));
  return v;
}
__device__ __forceinline__ float wred_sum(float v) {
#pragma unroll
  for (int m = 32; m > 0; m >>= 1) v += __shfl_xor(v, m, 64);
  return v;
}

// ---------------- patchify: images (N,C,224,224) -> patches hi/lo (6272, 768) bf16 ----------------
__global__ __launch_bounds__(256) void patchify_kernel(const float* __restrict__ img,
                                                       ushort_t* __restrict__ phi,
                                                       ushort_t* __restrict__ plo) {
  int idx = blockIdx.x * 256 + threadIdx.x;
  if (idx >= 6272 * 768) return;
  int mp = idx / 768, kk = idx - mp * 768;
  int n = mp / 196, p = mp - n * 196;
  int py = p / 14, px = p - py * 14;
  int c = kk >> 8, r = kk & 255;
  int u = r >> 4, vv = r & 15;
  float val = img[((size_t)(n * 3 + c) * 224 + py * 16 + u) * 224 + px * 16 + vv];
  ushort_t hi = f2bf_rn(val);
  phi[idx] = hi;
  plo[idx] = f2bf_rn(val - bf2f(hi));
}

// x[n,0,:] = cls + pos[0]
__global__ __launch_bounds__(256) void cls_init_kernel(const float* __restrict__ cls_tok,
                                                       const float* __restrict__ pos,
                                                       float* __restrict__ x) {
  int idx = blockIdx.x * 256 + threadIdx.x;  // 32*768
  int n = idx / 768, d = idx - n * 768;
  x[(size_t)n * S_ * D_ + d] = cls_tok[d] + pos[d];
}

// ---------------- weight transpose + hi/lo split: W (K x N fp32) -> Wt hi/lo (N x K bf16) -------
__global__ __launch_bounds__(256) void wconvert_kernel(const float* __restrict__ W,
                                                       ushort_t* __restrict__ Thi,
                                                       ushort_t* __restrict__ Tlo, int K, int N) {
  __shared__ float T[32][36];
  int n0 = blockIdx.x * 32, k0 = blockIdx.y * 32;
  int t = threadIdx.x;
  int r = t >> 3, c4 = (t & 7) * 4;
  float4 v = *(const float4*)&W[(size_t)(k0 + r) * N + n0 + c4];
  T[c4 + 0][r] = v.x;
  T[c4 + 1][r] = v.y;
  T[c4 + 2][r] = v.z;
  T[c4 + 3][r] = v.w;
  __syncthreads();
  ushort4 hi, lo;
  float a;
  a = T[r][c4 + 0]; hi.x = f2bf_rn(a); lo.x = f2bf_rn(a - bf2f(hi.x));
  a = T[r][c4 + 1]; hi.y = f2bf_rn(a); lo.y = f2bf_rn(a - bf2f(hi.y));
  a = T[r][c4 + 2]; hi.z = f2bf_rn(a); lo.z = f2bf_rn(a - bf2f(hi.z));
  a = T[r][c4 + 3]; hi.w = f2bf_rn(a); lo.w = f2bf_rn(a - bf2f(hi.w));
  size_t o = (size_t)(n0 + r) * K + k0 + c4;
  *(ushort4*)&Thi[o] = hi;
  *(ushort4*)&Tlo[o] = lo;
}

// ---------------- split-bf16 MFMA GEMM: C = A(MxK) * B(KxN), Bt given NxK --------------
// 128x128 tile, BK=32, 4 waves each 64x64 (4x4 of 16x16x32 MFMA), 3-term hi/lo split.
#define EPI_PATCH 1
#define EPI_GELU 2
#define EPI_RES 3
#define LDST 40  // LDS row stride in shorts (+8 pad)

template <int EPI>
__global__ __launch_bounds__(256) void gemm_mfma(
    const ushort_t* __restrict__ Ahi, const ushort_t* __restrict__ Alo,
    const ushort_t* __restrict__ Bhi, const ushort_t* __restrict__ Blo,
    const float* __restrict__ bias, float* __restrict__ Cf, ushort_t* __restrict__ Chi,
    ushort_t* __restrict__ Clo, int M, int K, int Nc, const float* __restrict__ pos) {
  __shared__ ushort_t As[2][128 * LDST];
  __shared__ ushort_t Bs[2][128 * LDST];
  int tid = threadIdx.x;
  int wave = tid >> 6, lane = tid & 63;
  int wr = (wave >> 1) * 64, wc = (wave & 1) * 64;
  int q = lane >> 4, l15 = lane & 15;
  int m0 = blockIdx.y * 128, n0 = blockIdx.x * 128;

  floatx4 acc[4][4];
#pragma unroll
  for (int i = 0; i < 4; ++i)
#pragma unroll
    for (int j = 0; j < 4; ++j)
#pragma unroll
      for (int e = 0; e < 4; ++e) acc[i][j][e] = 0.f;

  int sr = tid >> 2;        // 0..63
  int kq = tid & 3;         // 16B chunk within 64B row

  for (int k0 = 0; k0 < K; k0 += 32) {
#pragma unroll
    for (int it = 0; it < 2; ++it) {
      int rr = it * 64 + sr;  // 0..127
      int gm = m0 + rr;
      if (gm > M - 1) gm = M - 1;
      size_t aoff = (size_t)gm * K + k0 + kq * 8;
      *(uint4*)&As[0][rr * LDST + kq * 8] = *(const uint4*)&Ahi[aoff];
      *(uint4*)&As[1][rr * LDST + kq * 8] = *(const uint4*)&Alo[aoff];
      size_t boff = (size_t)(n0 + rr) * K + k0 + kq * 8;
      *(uint4*)&Bs[0][rr * LDST + kq * 8] = *(const uint4*)&Bhi[boff];
      *(uint4*)&Bs[1][rr * LDST + kq * 8] = *(const uint4*)&Blo[boff];
    }
    __syncthreads();
    short8x ah[4], al[4], bh[4], bl[4];
    int abase = (wr + l15) * LDST + q * 8;
    int bbase = (wc + l15) * LDST + q * 8;
#pragma unroll
    for (int i = 0; i < 4; ++i) {
      ah[i] = *(const short8x*)&As[0][abase + i * 16 * LDST];
      al[i] = *(const short8x*)&As[1][abase + i * 16 * LDST];
      bh[i] = *(const short8x*)&Bs[0][bbase + i * 16 * LDST];
      bl[i] = *(const short8x*)&Bs[1][bbase + i * 16 * LDST];
    }
#pragma unroll
    for (int i = 0; i < 4; ++i)
#pragma unroll
      for (int j = 0; j < 4; ++j) {
        acc[i][j] = __builtin_amdgcn_mfma_f32_16x16x32_bf16(ah[i], bh[j], acc[i][j], 0, 0, 0);
        acc[i][j] = __builtin_amdgcn_mfma_f32_16x16x32_bf16(ah[i], bl[j], acc[i][j], 0, 0, 0);
        acc[i][j] = __builtin_amdgcn_mfma_f32_16x16x32_bf16(al[i], bh[j], acc[i][j], 0, 0, 0);
      }
    __syncthreads();
  }

  // epilogue: D row=q*4+reg, col=l15 within each 16x16 tile
#pragma unroll
  for (int i = 0; i < 4; ++i) {
#pragma unroll
    for (int j = 0; j < 4; ++j) {
      int col = n0 + wc + j * 16 + l15;
#pragma unroll
      for (int r4 = 0; r4 < 4; ++r4) {
        int gr = m0 + wr + i * 16 + q * 4 + r4;
        if (gr >= M) continue;
        float v = acc[i][j][r4] + bias[col];
        if (EPI == EPI_PATCH) {
          int n = gr / 196, t = gr - n * 196 + 1;
          Cf[((size_t)n * S_ + t) * 768 + col] = v + pos[(size_t)t * 768 + col];
        } else if (EPI == EPI_GELU) {
          float g = 0.5f * v * (1.f + erff(v * 0.70710678118654752f));
          ushort_t hi = f2bf_rn(g);
          size_t o = (size_t)gr * FF_ + col;
          Chi[o] = hi;
          Clo[o] = f2bf_rn(g - bf2f(hi));
        } else {  // EPI_RES
          Cf[(size_t)gr * 768 + col] += v;
        }
      }
    }
  }
}

// ---------------- LayerNorm: one wave per token, emits bf16 hi/lo ----------------
__global__ __launch_bounds__(256) void ln_kernel(const float* __restrict__ x,
                                                 ushort_t* __restrict__ hhi,
                                                 ushort_t* __restrict__ hlo,
                                                 const float* __restrict__ w,
                                                 const float* __restrict__ b) {
  int tok = blockIdx.x * 4 + (threadIdx.x >> 6);
  int lane = threadIdx.x & 63;
  const float* xr = x + (size_t)tok * 768;
  float4 v[3];
  float s = 0.f, s2 = 0.f;
#pragma unroll
  for (int i = 0; i < 3; ++i) {
    v[i] = *(const float4*)&xr[i * 256 + lane * 4];
    s += v[i].x + v[i].y + v[i].z + v[i].w;
    s2 += v[i].x * v[i].x + v[i].y * v[i].y + v[i].z * v[i].z + v[i].w * v[i].w;
  }
  s = wred_sum(s);
  s2 = wred_sum(s2);
  float mu = s * (1.f / 768.f);
  float var = s2 * (1.f / 768.f) - mu * mu;
  float rs = rsqrtf(var + 1e-5f);
#pragma unroll
  for (int i = 0; i < 3; ++i) {
    float4 wv = *(const float4*)&w[i * 256 + lane * 4];
    float4 bv = *(const float4*)&b[i * 256 + lane * 4];
    float o0 = (v[i].x - mu) * rs * wv.x + bv.x;
    float o1 = (v[i].y - mu) * rs * wv.y + bv.y;
    float o2 = (v[i].z - mu) * rs * wv.z + bv.z;
    float o3 = (v[i].w - mu) * rs * wv.w + bv.w;
    ushort4 oh, ol;
    oh.x = f2bf_rn(o0); ol.x = f2bf_rn(o0 - bf2f(oh.x));
    oh.y = f2bf_rn(o1); ol.y = f2bf_rn(o1 - bf2f(oh.y));
    oh.z = f2bf_rn(o2); ol.z = f2bf_rn(o2 - bf2f(oh.z));
    oh.w = f2bf_rn(o3); ol.w = f2bf_rn(o3 - bf2f(oh.w));
    size_t o = (size_t)tok * 768 + i * 256 + lane * 4;
    *(ushort4*)&hhi[o] = oh;
    *(ushort4*)&hlo[o] = ol;
  }
}

// ---------------- QKV projection: per-head 64x64, reads bf16 hi/lo h ----------------
__global__ __launch_bounds__(256) void qkv_kernel(
    const ushort_t* __restrict__ hhi, const ushort_t* __restrict__ hlo,
    const float* __restrict__ Wq, const float* __restrict__ Wk, const float* __restrict__ Wv,
    const float* __restrict__ bq, const float* __restrict__ bk, const float* __restrict__ bv,
    float* __restrict__ qo, float* __restrict__ ko, float* __restrict__ vo) {
  __shared__ float Hs[64 * 68];  // [d][m] transposed
  __shared__ float Ws[64 * 68];  // [d][e]
  int tid = threadIdx.x;
  int which = blockIdx.z;
  const float* W = which == 0 ? Wq : (which == 1 ? Wk : Wv);
  const float* bb = which == 0 ? bq : (which == 1 ? bk : bv);
  float* out = which == 0 ? qo : (which == 1 ? ko : vo);
  int head = blockIdx.y;
  int m0 = blockIdx.x * 64;
#pragma unroll
  for (int it = 0; it < 4; ++it) {
    int f4 = it * 256 + tid;
    int row = f4 >> 4, c4 = f4 & 15;
    int gr = m0 + row;
    if (gr > MTOK - 1) gr = MTOK - 1;
    size_t ho = (size_t)gr * 768 + head * 64 + c4 * 4;
    ushort4 ah = *(const ushort4*)&hhi[ho];
    ushort4 al = *(const ushort4*)&hlo[ho];
    Hs[(c4 * 4 + 0) * 68 + row] = bf2f(ah.x) + bf2f(al.x);
    Hs[(c4 * 4 + 1) * 68 + row] = bf2f(ah.y) + bf2f(al.y);
    Hs[(c4 * 4 + 2) * 68 + row] = bf2f(ah.z) + bf2f(al.z);
    Hs[(c4 * 4 + 3) * 68 + row] = bf2f(ah.w) + bf2f(al.w);
    float4 wv = *(const float4*)&W[(size_t)head * 4096 + row * 64 + c4 * 4];
    *(float4*)&Ws[row * 68 + c4 * 4] = wv;
  }
  __syncthreads();
  int tx = tid & 15, ty = tid >> 4;
  float acc[4][4];
#pragma unroll
  for (int i = 0; i < 4; ++i)
#pragma unroll
    for (int j = 0; j < 4; ++j) acc[i][j] = 0.f;
#pragma unroll 4
  for (int kk = 0; kk < 64; ++kk) {
    float4 a = *(const float4*)&Hs[kk * 68 + ty * 4];
    float4 bf = *(const float4*)&Ws[kk * 68 + tx * 4];
    float av[4] = {a.x, a.y, a.z, a.w};
    float bvv[4] = {bf.x, bf.y, bf.z, bf.w};
#pragma unroll
    for (int i = 0; i < 4; ++i)
#pragma unroll
      for (int j = 0; j < 4; ++j) acc[i][j] += av[i] * bvv[j];
  }
#pragma unroll
  for (int i = 0; i < 4; ++i) {
    int grow = m0 + ty * 4 + i;
    if (grow >= MTOK) break;
#pragma unroll
    for (int j = 0; j < 4; ++j) {
      int e = tx * 4 + j;
      out[(size_t)grow * 768 + head * 64 + e] = acc[i][j] + bb[head * 64 + e];
    }
  }
}

// ---------------- fused flash attention: block = (qchunk64, head, n) ----------------
__global__ __launch_bounds__(256) void attn_kernel(const float* __restrict__ Q,
                                                   const float* __restrict__ Kb,
                                                   const float* __restrict__ Vb,
                                                   float* __restrict__ X) {
  __shared__ float Qs[64 * 68];
  __shared__ float Kt[64 * 68];
  __shared__ float Vt[64 * 68];
  __shared__ float Ps[4][8][64];
  int tid = threadIdx.x;
  int w = tid >> 6, lane = tid & 63;
  int qc = blockIdx.x, hh = blockIdx.y, n = blockIdx.z;
  int q0 = qc * 64;
#pragma unroll
  for (int it = 0; it < 4; ++it) {
    int f4 = it * 256 + tid;
    int row = f4 >> 4, c4 = f4 & 15;
    int gr = q0 + row;
    if (gr > S_ - 1) gr = S_ - 1;
    float4 qv = *(const float4*)&Q[((size_t)n * S_ + gr) * 768 + hh * 64 + c4 * 4];
    *(float4*)&Qs[row * 68 + c4 * 4] = qv;
  }
  float m[2][8], l[2][8], o[2][8];
#pragma unroll
  for (int g = 0; g < 2; ++g)
#pragma unroll
    for (int r = 0; r < 8; ++r) {
      m[g][r] = -INFINITY;
      l[g][r] = 0.f;
      o[g][r] = 0.f;
    }

  for (int t = 0; t < 4; ++t) {
    __syncthreads();
#pragma unroll
    for (int it = 0; it < 4; ++it) {
      int f4 = it * 256 + tid;
      int row = f4 >> 4, c4 = f4 & 15;
      int gk = t * 64 + row;
      if (gk > S_ - 1) gk = S_ - 1;
      size_t base = ((size_t)n * S_ + gk) * 768 + hh * 64 + c4 * 4;
      *(float4*)&Kt[row * 68 + c4 * 4] = *(const float4*)&Kb[base];
      *(float4*)&Vt[row * 68 + c4 * 4] = *(const float4*)&Vb[base];
    }
    __syncthreads();
    int jj = t * 64 + lane;
    bool valid = jj < S_;
    for (int g = 0; g < 2; ++g) {
      int rbase = w * 16 + g * 8;
      float s[8];
#pragma unroll
      for (int r = 0; r < 8; ++r) s[r] = 0.f;
#pragma unroll 4
      for (int e4 = 0; e4 < 16; ++e4) {
        float4 kv = *(const float4*)&Kt[lane * 68 + e4 * 4];
#pragma unroll
        for (int r = 0; r < 8; ++r) {
          float4 qv = *(const float4*)&Qs[(rbase + r) * 68 + e4 * 4];
          s[r] += qv.x * kv.x + qv.y * kv.y + qv.z * kv.z + qv.w * kv.w;
        }
      }
#pragma unroll
      for (int r = 0; r < 8; ++r) {
        float sv = valid ? s[r] * 0.125f : -INFINITY;
        float tm = wred_max(sv);
        float mn = fmaxf(m[g][r], tm);
        float alpha = expf(m[g][r] - mn);
        float p = expf(sv - mn);
        float psum = wred_sum(p);
        l[g][r] = l[g][r] * alpha + psum;
        o[g][r] *= alpha;
        m[g][r] = mn;
        Ps[w][r][lane] = p;
      }
      __syncthreads();
#pragma unroll 8
      for (int j = 0; j < 64; ++j) {
        float vv = Vt[j * 68 + lane];
#pragma unroll
        for (int r = 0; r < 8; ++r) o[g][r] += Ps[w][r][j] * vv;
      }
      __syncthreads();
    }
  }
#pragma unroll
  for (int g = 0; g < 2; ++g)
#pragma unroll
    for (int r = 0; r < 8; ++r) {
      int row = q0 + w * 16 + g * 8 + r;
      if (row < S_) X[((size_t)n * S_ + row) * 768 + hh * 64 + lane] += o[g][r] / l[g][r];
    }
}

// ---------------- classifier head + softmax: one block per sample ----------------
__global__ __launch_bounds__(256) void head_kernel(const float* __restrict__ x,
                                                   const float* __restrict__ Wout,
                                                   const float* __restrict__ bout,
                                                   float* __restrict__ out) {
  __shared__ float cls[768];
  __shared__ float red[4];
  int n = blockIdx.x, tid = threadIdx.x;
  int w = tid >> 6, lane = tid & 63;
  for (int d = tid; d < 768; d += 256) cls[d] = x[(size_t)n * S_ * D_ + d];
  __syncthreads();
  int j0 = tid * 4;
  bool act = j0 < 1000;
  float a0 = 0.f, a1 = 0.f, a2 = 0.f, a3 = 0.f;
  if (act) {
    for (int kk = 0; kk < 768; ++kk) {
      float c = cls[kk];
      float4 wv = *(const float4*)&Wout[(size_t)kk * 1000 + j0];
      a0 += c * wv.x;
      a1 += c * wv.y;
      a2 += c * wv.z;
      a3 += c * wv.w;
    }
    a0 += bout[j0];
    a1 += bout[j0 + 1];
    a2 += bout[j0 + 2];
    a3 += bout[j0 + 3];
  }
  float mx = act ? fmaxf(fmaxf(a0, a1), fmaxf(a2, a3)) : -INFINITY;
  mx = wred_max(mx);
  if (lane == 0) red[w] = mx;
  __syncthreads();
  mx = fmaxf(fmaxf(red[0], red[1]), fmaxf(red[2], red[3]));
  __syncthreads();
  float e0 = 0.f, e1 = 0.f, e2 = 0.f, e3 = 0.f, ss = 0.f;
  if (act) {
    e0 = expf(a0 - mx);
    e1 = expf(a1 - mx);
    e2 = expf(a2 - mx);
    e3 = expf(a3 - mx);
    ss = e0 + e1 + e2 + e3;
  }
  ss = wred_sum(ss);
  if (lane == 0) red[w] = ss;
  __syncthreads();
  ss = red[0] + red[1] + red[2] + red[3];
  if (act) {
    float inv = 1.f / ss;
    out[(size_t)n * 1000 + j0] = e0 * inv;
    out[(size_t)n * 1000 + j0 + 1] = e1 * inv;
    out[(size_t)n * 1000 + j0 + 2] = e2 * inv;
    out[(size_t)n * 1000 + j0 + 3] = e3 * inv;
  }
}

extern "C" void kernel_launch(void* const* d_in, const int* in_sizes, int n_in, void* d_out,
                              int out_size, void* d_ws, size_t ws_size, hipStream_t stream) {
  const float* images = (const float*)d_in[0];
  const float* Wm = (const float*)d_in[1];
  const float* bm = (const float*)d_in[2];
  const float* cls_tok = (const float*)d_in[3];
  const float* pos_emb = (const float*)d_in[4];
  const float* ln1_w = (const float*)d_in[5];
  const float* ln1_b = (const float*)d_in[6];
  const float* Wq = (const float*)d_in[7];
  const float* bq = (const float*)d_in[8];
  const float* Wk = (const float*)d_in[9];
  const float* bk = (const float*)d_in[10];
  const float* Wv = (const float*)d_in[11];
  const float* bv = (const float*)d_in[12];
  const float* ln2_w = (const float*)d_in[13];
  const float* ln2_b = (const float*)d_in[14];
  const float* W1 = (const float*)d_in[15];
  const float* b1 = (const float*)d_in[16];
  const float* W2 = (const float*)d_in[17];
  const float* b2 = (const float*)d_in[18];
  const float* Wout = (const float*)d_in[19];
  const float* bout = (const float*)d_in[20];
  float* out = (float*)d_out;

  char* base = (char*)d_ws;
  float* x = (float*)base;                                   // ND fp32
  ushort_t* hhi = (ushort_t*)(base + (size_t)ND * 4);        // ND bf16
  ushort_t* hlo = hhi + (size_t)ND;                          // ND bf16
  char* R = base + (size_t)ND * 8;                           // big overlay region
  float* qb = (float*)R;
  float* kb = qb + (size_t)ND;
  float* vb = kb + (size_t)ND;
  ushort_t* ghi = (ushort_t*)R;                              // MTOK*FF bf16
  ushort_t* glo = ghi + (size_t)MTOK * FF_;
  ushort_t* phi = (ushort_t*)R;                              // patches
  ushort_t* plo = phi + (size_t)6272 * 768;
  char* WB = R + (size_t)MTOK * FF_ * 4;                     // weight scratch
  ushort_t* w1hi = (ushort_t*)WB;
  ushort_t* w1lo = w1hi + (size_t)768 * FF_;
  ushort_t* w2hi = w1lo + (size_t)768 * FF_;
  ushort_t* w2lo = w2hi + (size_t)768 * FF_;

  patchify_kernel<<<(6272 * 768 + 255) / 256, 256, 0, stream>>>(images, phi, plo);
  // Wm (768x768) -> transposed hi/lo (overlays w1 scratch)
  wconvert_kernel<<<dim3(24, 24), 256, 0, stream>>>(Wm, w1hi, w1lo, 768, 768);
  gemm_mfma<EPI_PATCH><<<dim3(6, 49), 256, 0, stream>>>(phi, plo, w1hi, w1lo, bm, x, nullptr,
                                                        nullptr, 6272, 768, 768, pos_emb);
  cls_init_kernel<<<(32 * 768) / 256, 256, 0, stream>>>(cls_tok, pos_emb, x);

  for (int l = 0; l < 8; ++l) {
    ln_kernel<<<MTOK / 4, 256, 0, stream>>>(x, hhi, hlo, ln1_w + l * 768, ln1_b + l * 768);
    qkv_kernel<<<dim3(99, 12, 3), 256, 0, stream>>>(
        hhi, hlo, Wq + (size_t)l * 49152, Wk + (size_t)l * 49152, Wv + (size_t)l * 49152,
        bq + l * 768, bk + l * 768, bv + l * 768, qb, kb, vb);
    attn_kernel<<<dim3(4, 12, 32), 256, 0, stream>>>(qb, kb, vb, x);
    ln_kernel<<<MTOK / 4, 256, 0, stream>>>(x, hhi, hlo, ln2_w + l * 768, ln2_b + l * 768);
    wconvert_kernel<<<dim3(96, 24), 256, 0, stream>>>(W1 + (size_t)l * 768 * FF_, w1hi, w1lo,
                                                      768, FF_);
    gemm_mfma<EPI_GELU><<<dim3(24, 50), 256, 0, stream>>>(hhi, hlo, w1hi, w1lo, b1 + l * FF_,
                                                          nullptr, ghi, glo, MTOK, 768, FF_,
                                                          nullptr);
    wconvert_kernel<<<dim3(24, 96), 256, 0, stream>>>(W2 + (size_t)l * FF_ * 768, w2hi, w2lo,
                                                      FF_, 768);
    gemm_mfma<EPI_RES><<<dim3(6, 50), 256, 0, stream>>>(ghi, glo, w2hi, w2lo, b2 + l * 768, x,
                                                        nullptr, nullptr, MTOK, FF_, 768,
                                                        nullptr);
  }
  head_kernel<<<32, 256, 0, stream>>>(x, Wout, bout, out);
}

// Round 3
// 3969.641 us; speedup vs baseline: 2.4672x; 1.3412x over previous
//
#include <hip/hip_runtime.h>
#include <math.h>

#define N_ 32
#define S_ 197
#define D_ 768
#define H_ 12
#define L_ 8
#define FF_ 3072
#define MTOK (N_ * S_)      // 6304
#define ND (N_ * S_ * D_)   // 4841472

typedef __attribute__((ext_vector_type(8))) short short8x;
typedef __attribute__((ext_vector_type(4))) float floatx4;
typedef unsigned short ushort_t;
typedef unsigned int uint_t;

__device__ __forceinline__ ushort_t f2bf_rn(float x) {
  uint_t u = __float_as_uint(x);
  uint_t r = (u + 0x7fff + ((u >> 16) & 1)) >> 16;
  return (ushort_t)r;
}
__device__ __forceinline__ float bf2f(ushort_t h) {
  return __uint_as_float(((uint_t)h) << 16);
}

// ---------------- patchify ----------------
__global__ __launch_bounds__(256) void patchify_kernel(const float* __restrict__ img,
                                                       ushort_t* __restrict__ phi,
                                                       ushort_t* __restrict__ plo) {
  int idx = blockIdx.x * 256 + threadIdx.x;
  if (idx >= 6272 * 768) return;
  int mp = idx / 768, kk = idx - mp * 768;
  int n = mp / 196, p = mp - n * 196;
  int py = p / 14, px = p - py * 14;
  int c = kk >> 8, r = kk & 255;
  int u = r >> 4, vv = r & 15;
  float val = img[((size_t)(n * 3 + c) * 224 + py * 16 + u) * 224 + px * 16 + vv];
  ushort_t hi = f2bf_rn(val);
  phi[idx] = hi;
  plo[idx] = f2bf_rn(val - bf2f(hi));
}

__global__ __launch_bounds__(256) void cls_init_kernel(const float* __restrict__ cls_tok,
                                                       const float* __restrict__ pos,
                                                       float* __restrict__ x) {
  int idx = blockIdx.x * 256 + threadIdx.x;  // 32*768
  int n = idx / 768, d = idx - n * 768;
  x[(size_t)n * S_ * D_ + d] = cls_tok[d] + pos[d];
}

// ---------------- weight transpose + hi/lo split ----------------
__global__ __launch_bounds__(256) void wconvert_kernel(const float* __restrict__ W,
                                                       ushort_t* __restrict__ Thi,
                                                       ushort_t* __restrict__ Tlo, int K, int N) {
  __shared__ float T[32][36];
  int n0 = blockIdx.x * 32, k0 = blockIdx.y * 32;
  int t = threadIdx.x;
  int r = t >> 3, c4 = (t & 7) * 4;
  float4 v = *(const float4*)&W[(size_t)(k0 + r) * N + n0 + c4];
  T[c4 + 0][r] = v.x;
  T[c4 + 1][r] = v.y;
  T[c4 + 2][r] = v.z;
  T[c4 + 3][r] = v.w;
  __syncthreads();
  ushort4 hi, lo;
  float a;
  a = T[r][c4 + 0]; hi.x = f2bf_rn(a); lo.x = f2bf_rn(a - bf2f(hi.x));
  a = T[r][c4 + 1]; hi.y = f2bf_rn(a); lo.y = f2bf_rn(a - bf2f(hi.y));
  a = T[r][c4 + 2]; hi.z = f2bf_rn(a); lo.z = f2bf_rn(a - bf2f(hi.z));
  a = T[r][c4 + 3]; hi.w = f2bf_rn(a); lo.w = f2bf_rn(a - bf2f(hi.w));
  size_t o = (size_t)(n0 + r) * K + k0 + c4;
  *(ushort4*)&Thi[o] = hi;
  *(ushort4*)&Tlo[o] = lo;
}

// ---------------- split-bf16 MFMA GEMM (MLP + patch embed) --------------
#define EPI_PATCH 1
#define EPI_GELU 2
#define EPI_RES 3
#define LDST 40

template <int EPI>
__global__ __launch_bounds__(256) void gemm_mfma(
    const ushort_t* __restrict__ Ahi, const ushort_t* __restrict__ Alo,
    const ushort_t* __restrict__ Bhi, const ushort_t* __restrict__ Blo,
    const float* __restrict__ bias, float* __restrict__ Cf, ushort_t* __restrict__ Chi,
    ushort_t* __restrict__ Clo, int M, int K, int Nc, const float* __restrict__ pos) {
  __shared__ ushort_t As[2][128 * LDST];
  __shared__ ushort_t Bs[2][128 * LDST];
  int tid = threadIdx.x;
  int wave = tid >> 6, lane = tid & 63;
  int wr = (wave >> 1) * 64, wc = (wave & 1) * 64;
  int q = lane >> 4, l15 = lane & 15;
  int m0 = blockIdx.y * 128, n0 = blockIdx.x * 128;

  floatx4 acc[4][4];
#pragma unroll
  for (int i = 0; i < 4; ++i)
#pragma unroll
    for (int j = 0; j < 4; ++j)
#pragma unroll
      for (int e = 0; e < 4; ++e) acc[i][j][e] = 0.f;

  int sr = tid >> 2;
  int kq = tid & 3;

  for (int k0 = 0; k0 < K; k0 += 32) {
#pragma unroll
    for (int it = 0; it < 2; ++it) {
      int rr = it * 64 + sr;
      int gm = m0 + rr;
      if (gm > M - 1) gm = M - 1;
      size_t aoff = (size_t)gm * K + k0 + kq * 8;
      *(uint4*)&As[0][rr * LDST + kq * 8] = *(const uint4*)&Ahi[aoff];
      *(uint4*)&As[1][rr * LDST + kq * 8] = *(const uint4*)&Alo[aoff];
      size_t boff = (size_t)(n0 + rr) * K + k0 + kq * 8;
      *(uint4*)&Bs[0][rr * LDST + kq * 8] = *(const uint4*)&Bhi[boff];
      *(uint4*)&Bs[1][rr * LDST + kq * 8] = *(const uint4*)&Blo[boff];
    }
    __syncthreads();
    short8x ah[4], al[4], bh[4], bl[4];
    int abase = (wr + l15) * LDST + q * 8;
    int bbase = (wc + l15) * LDST + q * 8;
#pragma unroll
    for (int i = 0; i < 4; ++i) {
      ah[i] = *(const short8x*)&As[0][abase + i * 16 * LDST];
      al[i] = *(const short8x*)&As[1][abase + i * 16 * LDST];
      bh[i] = *(const short8x*)&Bs[0][bbase + i * 16 * LDST];
      bl[i] = *(const short8x*)&Bs[1][bbase + i * 16 * LDST];
    }
#pragma unroll
    for (int i = 0; i < 4; ++i)
#pragma unroll
      for (int j = 0; j < 4; ++j) {
        acc[i][j] = __builtin_amdgcn_mfma_f32_16x16x32_bf16(ah[i], bh[j], acc[i][j], 0, 0, 0);
        acc[i][j] = __builtin_amdgcn_mfma_f32_16x16x32_bf16(ah[i], bl[j], acc[i][j], 0, 0, 0);
        acc[i][j] = __builtin_amdgcn_mfma_f32_16x16x32_bf16(al[i], bh[j], acc[i][j], 0, 0, 0);
      }
    __syncthreads();
  }

#pragma unroll
  for (int i = 0; i < 4; ++i) {
#pragma unroll
    for (int j = 0; j < 4; ++j) {
      int col = n0 + wc + j * 16 + l15;
#pragma unroll
      for (int r4 = 0; r4 < 4; ++r4) {
        int gr = m0 + wr + i * 16 + q * 4 + r4;
        if (gr >= M) continue;
        float v = acc[i][j][r4] + bias[col];
        if (EPI == EPI_PATCH) {
          int n = gr / 196, t = gr - n * 196 + 1;
          Cf[((size_t)n * S_ + t) * 768 + col] = v + pos[(size_t)t * 768 + col];
        } else if (EPI == EPI_GELU) {
          float g = 0.5f * v * (1.f + erff(v * 0.70710678118654752f));
          ushort_t hi = f2bf_rn(g);
          size_t o = (size_t)gr * FF_ + col;
          Chi[o] = hi;
          Clo[o] = f2bf_rn(g - bf2f(hi));
        } else {
          Cf[(size_t)gr * 768 + col] += v;
        }
      }
    }
  }
}

// ---------------- LayerNorm -> bf16 hi/lo ----------------
__global__ __launch_bounds__(256) void ln_kernel(const float* __restrict__ x,
                                                 ushort_t* __restrict__ hhi,
                                                 ushort_t* __restrict__ hlo,
                                                 const float* __restrict__ w,
                                                 const float* __restrict__ b) {
  int tok = blockIdx.x * 4 + (threadIdx.x >> 6);
  int lane = threadIdx.x & 63;
  const float* xr = x + (size_t)tok * 768;
  float4 v[3];
  float s = 0.f, s2 = 0.f;
#pragma unroll
  for (int i = 0; i < 3; ++i) {
    v[i] = *(const float4*)&xr[i * 256 + lane * 4];
    s += v[i].x + v[i].y + v[i].z + v[i].w;
    s2 += v[i].x * v[i].x + v[i].y * v[i].y + v[i].z * v[i].z + v[i].w * v[i].w;
  }
#pragma unroll
  for (int m = 32; m > 0; m >>= 1) { s += __shfl_xor(s, m, 64); s2 += __shfl_xor(s2, m, 64); }
  float mu = s * (1.f / 768.f);
  float var = s2 * (1.f / 768.f) - mu * mu;
  float rs = rsqrtf(var + 1e-5f);
#pragma unroll
  for (int i = 0; i < 3; ++i) {
    float4 wv = *(const float4*)&w[i * 256 + lane * 4];
    float4 bv = *(const float4*)&b[i * 256 + lane * 4];
    float o0 = (v[i].x - mu) * rs * wv.x + bv.x;
    float o1 = (v[i].y - mu) * rs * wv.y + bv.y;
    float o2 = (v[i].z - mu) * rs * wv.z + bv.z;
    float o3 = (v[i].w - mu) * rs * wv.w + bv.w;
    ushort4 oh, ol;
    oh.x = f2bf_rn(o0); ol.x = f2bf_rn(o0 - bf2f(oh.x));
    oh.y = f2bf_rn(o1); ol.y = f2bf_rn(o1 - bf2f(oh.y));
    oh.z = f2bf_rn(o2); ol.z = f2bf_rn(o2 - bf2f(oh.z));
    oh.w = f2bf_rn(o3); ol.w = f2bf_rn(o3 - bf2f(oh.w));
    size_t o = (size_t)tok * 768 + i * 256 + lane * 4;
    *(ushort4*)&hhi[o] = oh;
    *(ushort4*)&hlo[o] = ol;
  }
}

// ---------------- QKV projection via MFMA: block = 128 tokens x head ----------------
#define KSTR 72  // LDS row stride in shorts for 64-wide K tiles

__global__ __launch_bounds__(256) void qkv_mfma(
    const ushort_t* __restrict__ hhi, const ushort_t* __restrict__ hlo,
    const float* __restrict__ Wq, const float* __restrict__ Wk, const float* __restrict__ Wv,
    const float* __restrict__ bq, const float* __restrict__ bk, const float* __restrict__ bv,
    ushort_t* __restrict__ qhi, ushort_t* __restrict__ qlo, ushort_t* __restrict__ khi,
    ushort_t* __restrict__ klo, ushort_t* __restrict__ vhi, ushort_t* __restrict__ vlo) {
  __shared__ ushort_t As[2][128 * KSTR];  // h tile: [tok][d]
  __shared__ ushort_t Ws[2][64 * KSTR];   // weight: [e][d] (transposed)
  int tid = threadIdx.x;
  int wave = tid >> 6, lane = tid & 63;
  int q = lane >> 4, l15 = lane & 15;
  int m0 = blockIdx.x * 128, h = blockIdx.y;
  int wm = wave >> 1, wj = wave & 1;

  // stage h tile hi/lo
#pragma unroll
  for (int p = 0; p < 2; ++p) {
    const ushort_t* src = p == 0 ? hhi : hlo;
#pragma unroll
    for (int it = 0; it < 4; ++it) {
      int idx = it * 256 + tid;
      int r = idx >> 3, c = idx & 7;
      int gm = m0 + r;
      if (gm > MTOK - 1) gm = MTOK - 1;
      *(uint4*)&As[p][r * KSTR + c * 8] = *(const uint4*)&src[(size_t)gm * 768 + h * 64 + c * 8];
    }
  }

  const float* Wmat[3] = {Wq + (size_t)h * 4096, Wk + (size_t)h * 4096, Wv + (size_t)h * 4096};
  const float* Bmat[3] = {bq + h * 64, bk + h * 64, bv + h * 64};
  ushort_t* Ohi[3] = {qhi, khi, vhi};
  ushort_t* Olo[3] = {qlo, klo, vlo};

  for (int mat = 0; mat < 3; ++mat) {
    __syncthreads();  // Ws reuse protection + (mat=0) As ready
    // stage W transposed: Ws[e][d] = W[d][e]
#pragma unroll
    for (int it = 0; it < 4; ++it) {
      int idx = it * 256 + tid;
      int r = idx >> 4, c4 = (idx & 15) * 4;  // r = d, c4 = e
      float4 wv = *(const float4*)&Wmat[mat][r * 64 + c4];
      float vals[4] = {wv.x, wv.y, wv.z, wv.w};
#pragma unroll
      for (int i = 0; i < 4; ++i) {
        ushort_t hi = f2bf_rn(vals[i]);
        Ws[0][(c4 + i) * KSTR + r] = hi;
        Ws[1][(c4 + i) * KSTR + r] = f2bf_rn(vals[i] - bf2f(hi));
      }
    }
    __syncthreads();

    floatx4 acc[4][2];
#pragma unroll
    for (int i = 0; i < 4; ++i)
#pragma unroll
      for (int j = 0; j < 2; ++j)
#pragma unroll
        for (int e = 0; e < 4; ++e) acc[i][j][e] = 0.f;

#pragma unroll
    for (int ks = 0; ks < 2; ++ks) {
      short8x bh[2], bl[2];
#pragma unroll
      for (int j = 0; j < 2; ++j) {
        int bb = (wj * 32 + j * 16 + l15) * KSTR + ks * 32 + q * 8;
        bh[j] = *(const short8x*)&Ws[0][bb];
        bl[j] = *(const short8x*)&Ws[1][bb];
      }
#pragma unroll
      for (int i = 0; i < 4; ++i) {
        int ab = (wm * 64 + i * 16 + l15) * KSTR + ks * 32 + q * 8;
        short8x ah = *(const short8x*)&As[0][ab];
        short8x al = *(const short8x*)&As[1][ab];
#pragma unroll
        for (int j = 0; j < 2; ++j) {
          acc[i][j] = __builtin_amdgcn_mfma_f32_16x16x32_bf16(ah, bh[j], acc[i][j], 0, 0, 0);
          acc[i][j] = __builtin_amdgcn_mfma_f32_16x16x32_bf16(ah, bl[j], acc[i][j], 0, 0, 0);
          acc[i][j] = __builtin_amdgcn_mfma_f32_16x16x32_bf16(al, bh[j], acc[i][j], 0, 0, 0);
        }
      }
    }
    // epilogue
#pragma unroll
    for (int i = 0; i < 4; ++i)
#pragma unroll
      for (int j = 0; j < 2; ++j) {
        int col = wj * 32 + j * 16 + l15;
        float bias = Bmat[mat][col];
#pragma unroll
        for (int r = 0; r < 4; ++r) {
          int tok = m0 + wm * 64 + i * 16 + q * 4 + r;
          if (tok >= MTOK) continue;
          float v = acc[i][j][r] + bias;
          ushort_t hi = f2bf_rn(v);
          size_t o = (size_t)tok * 768 + h * 64 + col;
          Ohi[mat][o] = hi;
          Olo[mat][o] = f2bf_rn(v - bf2f(hi));
        }
      }
  }
}

// ---------------- MFMA flash attention: block = (qchunk64, head, n) ----------------
__global__ __launch_bounds__(256) void attn_mfma(
    const ushort_t* __restrict__ qhi, const ushort_t* __restrict__ qlo,
    const ushort_t* __restrict__ khi, const ushort_t* __restrict__ klo,
    const ushort_t* __restrict__ vhi, const ushort_t* __restrict__ vlo,
    float* __restrict__ X) {
  __shared__ ushort_t Qs[2][64 * KSTR];  // [qrow][d]
  __shared__ ushort_t Ks[2][64 * KSTR];  // [key][d]; later aliased as P [qrow][key]
  __shared__ ushort_t Vs[2][64 * KSTR];  // transposed [d][key]
  int tid = threadIdx.x;
  int wave = tid >> 6, lane = tid & 63;
  int q = lane >> 4, l15 = lane & 15;
  int qc = blockIdx.x, h = blockIdx.y, n = blockIdx.z;
  int q0 = qc * 64;
  int row0 = wave * 16;

  // stage Q (once)
#pragma unroll
  for (int p = 0; p < 2; ++p) {
    const ushort_t* src = p == 0 ? qhi : qlo;
#pragma unroll
    for (int it = 0; it < 2; ++it) {
      int idx = it * 256 + tid;
      int r = idx >> 3, c = idx & 7;
      int gr = q0 + r;
      if (gr > S_ - 1) gr = S_ - 1;
      *(uint4*)&Qs[p][r * KSTR + c * 8] =
          *(const uint4*)&src[((size_t)n * S_ + gr) * 768 + h * 64 + c * 8];
    }
  }
  __syncthreads();
  // hoist Q A-fragments (Qs is never overwritten)
  short8x qa_h[2], qa_l[2];
#pragma unroll
  for (int ks = 0; ks < 2; ++ks) {
    int ab = (row0 + l15) * KSTR + ks * 32 + q * 8;
    qa_h[ks] = *(const short8x*)&Qs[0][ab];
    qa_l[ks] = *(const short8x*)&Qs[1][ab];
  }

  float mrow[4], lrow[4];
  floatx4 oa[4];
#pragma unroll
  for (int r = 0; r < 4; ++r) { mrow[r] = -INFINITY; lrow[r] = 0.f; }
#pragma unroll
  for (int j = 0; j < 4; ++j)
#pragma unroll
    for (int e = 0; e < 4; ++e) oa[j][e] = 0.f;

  for (int t = 0; t < 4; ++t) {
    __syncthreads();  // prior tile's P/V consumers done
    // stage K tile [key][d]
#pragma unroll
    for (int p = 0; p < 2; ++p) {
      const ushort_t* src = p == 0 ? khi : klo;
#pragma unroll
      for (int it = 0; it < 2; ++it) {
        int idx = it * 256 + tid;
        int r = idx >> 3, c = idx & 7;
        int gk = t * 64 + r;
        if (gk > S_ - 1) gk = S_ - 1;
        *(uint4*)&Ks[p][r * KSTR + c * 8] =
            *(const uint4*)&src[((size_t)n * S_ + gk) * 768 + h * 64 + c * 8];
      }
    }
    // stage V tile transposed [d][key]: wave w covers keys w*16..+15, lane d = tid&63
    {
      int d = tid & 63, kg = tid >> 6;
#pragma unroll
      for (int p = 0; p < 2; ++p) {
        const ushort_t* src = p == 0 ? vhi : vlo;
#pragma unroll
        for (int k4 = 0; k4 < 4; ++k4) {
          ushort4 pk;
          ushort_t tmp[4];
#pragma unroll
          for (int i = 0; i < 4; ++i) {
            int gk = t * 64 + kg * 16 + k4 * 4 + i;
            if (gk > S_ - 1) gk = S_ - 1;
            tmp[i] = src[((size_t)n * S_ + gk) * 768 + h * 64 + d];
          }
          pk.x = tmp[0]; pk.y = tmp[1]; pk.z = tmp[2]; pk.w = tmp[3];
          *(ushort4*)&Vs[p][d * KSTR + kg * 16 + k4 * 4] = pk;
        }
      }
    }
    __syncthreads();

    // QK^T: scores for this wave's 16 rows x 64 keys
    floatx4 sc[4];
#pragma unroll
    for (int j = 0; j < 4; ++j) {
#pragma unroll
      for (int e = 0; e < 4; ++e) sc[j][e] = 0.f;
#pragma unroll
      for (int ks = 0; ks < 2; ++ks) {
        int bb = (j * 16 + l15) * KSTR + ks * 32 + q * 8;
        short8x kb_h = *(const short8x*)&Ks[0][bb];
        short8x kb_l = *(const short8x*)&Ks[1][bb];
        sc[j] = __builtin_amdgcn_mfma_f32_16x16x32_bf16(qa_h[ks], kb_h, sc[j], 0, 0, 0);
        sc[j] = __builtin_amdgcn_mfma_f32_16x16x32_bf16(qa_h[ks], kb_l, sc[j], 0, 0, 0);
        sc[j] = __builtin_amdgcn_mfma_f32_16x16x32_bf16(qa_l[ks], kb_h, sc[j], 0, 0, 0);
      }
    }
    __syncthreads();  // all waves done reading Ks before P overwrites it

    // online softmax + P write (P aliases Ks region)
    bool kvalid[4];
#pragma unroll
    for (int j = 0; j < 4; ++j) kvalid[j] = (t * 64 + j * 16 + l15) < S_;
#pragma unroll
    for (int r = 0; r < 4; ++r) {
      float sv[4];
#pragma unroll
      for (int j = 0; j < 4; ++j) sv[j] = kvalid[j] ? sc[j][r] * 0.125f : -INFINITY;
      float mx = fmaxf(fmaxf(sv[0], sv[1]), fmaxf(sv[2], sv[3]));
#pragma unroll
      for (int msk = 1; msk < 16; msk <<= 1) mx = fmaxf(mx, __shfl_xor(mx, msk, 64));
      float mn = fmaxf(mrow[r], mx);
      float al = expf(mrow[r] - mn);
      float p[4], ps = 0.f;
#pragma unroll
      for (int j = 0; j < 4; ++j) { p[j] = expf(sv[j] - mn); ps += p[j]; }
#pragma unroll
      for (int msk = 1; msk < 16; msk <<= 1) ps += __shfl_xor(ps, msk, 64);
      lrow[r] = lrow[r] * al + ps;
      mrow[r] = mn;
#pragma unroll
      for (int j = 0; j < 4; ++j) oa[j][r] *= al;
      int prow = (row0 + q * 4 + r) * KSTR;
#pragma unroll
      for (int j = 0; j < 4; ++j) {
        ushort_t phv = f2bf_rn(p[j]);
        Ks[0][prow + j * 16 + l15] = phv;
        Ks[1][prow + j * 16 + l15] = f2bf_rn(p[j] - bf2f(phv));
      }
    }

    // PV: O += P * V   (A = P [qrow][key] from own strip, B = Vs [d][key])
#pragma unroll
    for (int ks = 0; ks < 2; ++ks) {
      int ab = (row0 + l15) * KSTR + ks * 32 + q * 8;
      short8x pa_h = *(const short8x*)&Ks[0][ab];
      short8x pa_l = *(const short8x*)&Ks[1][ab];
#pragma unroll
      for (int j = 0; j < 4; ++j) {
        int bb = (j * 16 + l15) * KSTR + ks * 32 + q * 8;
        short8x vb_h = *(const short8x*)&Vs[0][bb];
        short8x vb_l = *(const short8x*)&Vs[1][bb];
        oa[j] = __builtin_amdgcn_mfma_f32_16x16x32_bf16(pa_h, vb_h, oa[j], 0, 0, 0);
        oa[j] = __builtin_amdgcn_mfma_f32_16x16x32_bf16(pa_h, vb_l, oa[j], 0, 0, 0);
        oa[j] = __builtin_amdgcn_mfma_f32_16x16x32_bf16(pa_l, vb_h, oa[j], 0, 0, 0);
      }
    }
  }

  // epilogue: X += O / l
#pragma unroll
  for (int r = 0; r < 4; ++r) {
    int row = q0 + row0 + q * 4 + r;
    if (row >= S_) continue;
    float invl = 1.f / lrow[r];
#pragma unroll
    for (int j = 0; j < 4; ++j)
      X[((size_t)n * S_ + row) * 768 + h * 64 + j * 16 + l15] += oa[j][r] * invl;
  }
}

// ---------------- classifier head + softmax ----------------
__global__ __launch_bounds__(256) void head_kernel(const float* __restrict__ x,
                                                   const float* __restrict__ Wout,
                                                   const float* __restrict__ bout,
                                                   float* __restrict__ out) {
  __shared__ float cls[768];
  __shared__ float red[4];
  int n = blockIdx.x, tid = threadIdx.x;
  int w = tid >> 6, lane = tid & 63;
  for (int d = tid; d < 768; d += 256) cls[d] = x[(size_t)n * S_ * D_ + d];
  __syncthreads();
  int j0 = tid * 4;
  bool act = j0 < 1000;
  float a0 = 0.f, a1 = 0.f, a2 = 0.f, a3 = 0.f;
  if (act) {
    for (int kk = 0; kk < 768; ++kk) {
      float c = cls[kk];
      float4 wv = *(const float4*)&Wout[(size_t)kk * 1000 + j0];
      a0 += c * wv.x;
      a1 += c * wv.y;
      a2 += c * wv.z;
      a3 += c * wv.w;
    }
    a0 += bout[j0];
    a1 += bout[j0 + 1];
    a2 += bout[j0 + 2];
    a3 += bout[j0 + 3];
  }
  float mx = act ? fmaxf(fmaxf(a0, a1), fmaxf(a2, a3)) : -INFINITY;
#pragma unroll
  for (int m = 32; m > 0; m >>= 1) mx = fmaxf(mx, __shfl_xor(mx, m, 64));
  if (lane == 0) red[w] = mx;
  __syncthreads();
  mx = fmaxf(fmaxf(red[0], red[1]), fmaxf(red[2], red[3]));
  __syncthreads();
  float e0 = 0.f, e1 = 0.f, e2 = 0.f, e3 = 0.f, ss = 0.f;
  if (act) {
    e0 = expf(a0 - mx);
    e1 = expf(a1 - mx);
    e2 = expf(a2 - mx);
    e3 = expf(a3 - mx);
    ss = e0 + e1 + e2 + e3;
  }
#pragma unroll
  for (int m = 32; m > 0; m >>= 1) ss += __shfl_xor(ss, m, 64);
  if (lane == 0) red[w] = ss;
  __syncthreads();
  ss = red[0] + red[1] + red[2] + red[3];
  if (act) {
    float inv = 1.f / ss;
    out[(size_t)n * 1000 + j0] = e0 * inv;
    out[(size_t)n * 1000 + j0 + 1] = e1 * inv;
    out[(size_t)n * 1000 + j0 + 2] = e2 * inv;
    out[(size_t)n * 1000 + j0 + 3] = e3 * inv;
  }
}

extern "C" void kernel_launch(void* const* d_in, const int* in_sizes, int n_in, void* d_out,
                              int out_size, void* d_ws, size_t ws_size, hipStream_t stream) {
  const float* images = (const float*)d_in[0];
  const float* Wm = (const float*)d_in[1];
  const float* bm = (const float*)d_in[2];
  const float* cls_tok = (const float*)d_in[3];
  const float* pos_emb = (const float*)d_in[4];
  const float* ln1_w = (const float*)d_in[5];
  const float* ln1_b = (const float*)d_in[6];
  const float* Wq = (const float*)d_in[7];
  const float* bq = (const float*)d_in[8];
  const float* Wk = (const float*)d_in[9];
  const float* bk = (const float*)d_in[10];
  const float* Wv = (const float*)d_in[11];
  const float* bv = (const float*)d_in[12];
  const float* ln2_w = (const float*)d_in[13];
  const float* ln2_b = (const float*)d_in[14];
  const float* W1 = (const float*)d_in[15];
  const float* b1 = (const float*)d_in[16];
  const float* W2 = (const float*)d_in[17];
  const float* b2 = (const float*)d_in[18];
  const float* Wout = (const float*)d_in[19];
  const float* bout = (const float*)d_in[20];
  float* out = (float*)d_out;

  char* base = (char*)d_ws;
  float* x = (float*)base;                              // ND fp32
  ushort_t* hhi = (ushort_t*)(base + (size_t)ND * 4);   // ND bf16
  ushort_t* hlo = hhi + (size_t)ND;
  char* R = base + (size_t)ND * 8;                      // overlay region
  ushort_t* qhi = (ushort_t*)R;                         // 6 bf16 planes (attn)
  ushort_t* qlo = qhi + (size_t)ND;
  ushort_t* khi = qlo + (size_t)ND;
  ushort_t* klo = khi + (size_t)ND;
  ushort_t* vhi = klo + (size_t)ND;
  ushort_t* vlo = vhi + (size_t)ND;
  ushort_t* ghi = (ushort_t*)R;                         // MLP hidden (same overlay)
  ushort_t* glo = ghi + (size_t)MTOK * FF_;
  ushort_t* phi = (ushort_t*)R;                         // patches (same overlay)
  ushort_t* plo = phi + (size_t)6272 * 768;
  char* WB = R + (size_t)MTOK * FF_ * 4;                // weight scratch
  ushort_t* w1hi = (ushort_t*)WB;
  ushort_t* w1lo = w1hi + (size_t)768 * FF_;
  ushort_t* w2hi = w1lo + (size_t)768 * FF_;
  ushort_t* w2lo = w2hi + (size_t)768 * FF_;

  patchify_kernel<<<(6272 * 768 + 255) / 256, 256, 0, stream>>>(images, phi, plo);
  wconvert_kernel<<<dim3(24, 24), 256, 0, stream>>>(Wm, w1hi, w1lo, 768, 768);
  gemm_mfma<EPI_PATCH><<<dim3(6, 49), 256, 0, stream>>>(phi, plo, w1hi, w1lo, bm, x, nullptr,
                                                        nullptr, 6272, 768, 768, pos_emb);
  cls_init_kernel<<<(32 * 768) / 256, 256, 0, stream>>>(cls_tok, pos_emb, x);

  for (int l = 0; l < 8; ++l) {
    ln_kernel<<<MTOK / 4, 256, 0, stream>>>(x, hhi, hlo, ln1_w + l * 768, ln1_b + l * 768);
    qkv_mfma<<<dim3(50, 12), 256, 0, stream>>>(
        hhi, hlo, Wq + (size_t)l * 49152, Wk + (size_t)l * 49152, Wv + (size_t)l * 49152,
        bq + l * 768, bk + l * 768, bv + l * 768, qhi, qlo, khi, klo, vhi, vlo);
    attn_mfma<<<dim3(4, 12, 32), 256, 0, stream>>>(qhi, qlo, khi, klo, vhi, vlo, x);
    ln_kernel<<<MTOK / 4, 256, 0, stream>>>(x, hhi, hlo, ln2_w + l * 768, ln2_b + l * 768);
    wconvert_kernel<<<dim3(96, 24), 256, 0, stream>>>(W1 + (size_t)l * 768 * FF_, w1hi, w1lo,
                                                      768, FF_);
    gemm_mfma<EPI_GELU><<<dim3(24, 50), 256, 0, stream>>>(hhi, hlo, w1hi, w1lo, b1 + l * FF_,
                                                          nullptr, ghi, glo, MTOK, 768, FF_,
                                                          nullptr);
    wconvert_kernel<<<dim3(24, 96), 256, 0, stream>>>(W2 + (size_t)l * FF_ * 768, w2hi, w2lo,
                                                      FF_, 768);
    gemm_mfma<EPI_RES><<<dim3(6, 50), 256, 0, stream>>>(ghi, glo, w2hi, w2lo, b2 + l * 768, x,
                                                        nullptr, nullptr, MTOK, FF_, 768,
                                                        nullptr);
  }
  head_kernel<<<32, 256, 0, stream>>>(x, Wout, bout, out);
}

// Round 5
// 3927.392 us; speedup vs baseline: 2.4937x; 1.0108x over previous
//
#include <hip/hip_runtime.h>
#include <math.h>

#define N_ 32
#define S_ 197
#define D_ 768
#define H_ 12
#define L_ 8
#define FF_ 3072
#define MTOK (N_ * S_)      // 6304
#define ND (N_ * S_ * D_)   // 4841472

typedef __attribute__((ext_vector_type(8))) short short8x;
typedef __attribute__((ext_vector_type(4))) float floatx4;
typedef unsigned short ushort_t;
typedef unsigned int uint_t;

__device__ __forceinline__ ushort_t f2bf_rn(float x) {
  uint_t u = __float_as_uint(x);
  uint_t r = (u + 0x7fff + ((u >> 16) & 1)) >> 16;
  return (ushort_t)r;
}
__device__ __forceinline__ float bf2f(ushort_t h) {
  return __uint_as_float(((uint_t)h) << 16);
}

// ---------------- patchify ----------------
__global__ __launch_bounds__(256) void patchify_kernel(const float* __restrict__ img,
                                                       ushort_t* __restrict__ phi,
                                                       ushort_t* __restrict__ plo) {
  int idx = blockIdx.x * 256 + threadIdx.x;
  if (idx >= 6272 * 768) return;
  int mp = idx / 768, kk = idx - mp * 768;
  int n = mp / 196, p = mp - n * 196;
  int py = p / 14, px = p - py * 14;
  int c = kk >> 8, r = kk & 255;
  int u = r >> 4, vv = r & 15;
  float val = img[((size_t)(n * 3 + c) * 224 + py * 16 + u) * 224 + px * 16 + vv];
  ushort_t hi = f2bf_rn(val);
  phi[idx] = hi;
  plo[idx] = f2bf_rn(val - bf2f(hi));
}

__global__ __launch_bounds__(256) void cls_init_kernel(const float* __restrict__ cls_tok,
                                                       const float* __restrict__ pos,
                                                       float* __restrict__ x) {
  int idx = blockIdx.x * 256 + threadIdx.x;  // 32*768
  int n = idx / 768, d = idx - n * 768;
  x[(size_t)n * S_ * D_ + d] = cls_tok[d] + pos[d];
}

// ---------------- weight transpose + hi/lo split ----------------
__global__ __launch_bounds__(256) void wconvert_kernel(const float* __restrict__ W,
                                                       ushort_t* __restrict__ Thi,
                                                       ushort_t* __restrict__ Tlo, int K, int N) {
  __shared__ float T[32][36];
  int n0 = blockIdx.x * 32, k0 = blockIdx.y * 32;
  int t = threadIdx.x;
  int r = t >> 3, c4 = (t & 7) * 4;
  float4 v = *(const float4*)&W[(size_t)(k0 + r) * N + n0 + c4];
  T[c4 + 0][r] = v.x;
  T[c4 + 1][r] = v.y;
  T[c4 + 2][r] = v.z;
  T[c4 + 3][r] = v.w;
  __syncthreads();
  ushort4 hi, lo;
  float a;
  a = T[r][c4 + 0]; hi.x = f2bf_rn(a); lo.x = f2bf_rn(a - bf2f(hi.x));
  a = T[r][c4 + 1]; hi.y = f2bf_rn(a); lo.y = f2bf_rn(a - bf2f(hi.y));
  a = T[r][c4 + 2]; hi.z = f2bf_rn(a); lo.z = f2bf_rn(a - bf2f(hi.z));
  a = T[r][c4 + 3]; hi.w = f2bf_rn(a); lo.w = f2bf_rn(a - bf2f(hi.w));
  size_t o = (size_t)(n0 + r) * K + k0 + c4;
  *(ushort4*)&Thi[o] = hi;
  *(ushort4*)&Tlo[o] = lo;
}

// ---------------- split-bf16 MFMA GEMM --------------
// grid: (mblocks, nblocks, KP). m-fastest for B-slab L2 reuse.
// EPI_ATOM (KP=2): both K-halves unsafeAtomicAdd into Cf (z==0 adds bias).
#define EPI_PATCH 1
#define EPI_GELU 2
#define EPI_ATOM 3
#define LDST 40

template <int EPI, int KP>
__global__ __launch_bounds__(256) void gemm_mfma(
    const ushort_t* __restrict__ Ahi, const ushort_t* __restrict__ Alo,
    const ushort_t* __restrict__ Bhi, const ushort_t* __restrict__ Blo,
    const float* __restrict__ bias, float* __restrict__ Cf, ushort_t* __restrict__ Chi,
    ushort_t* __restrict__ Clo, int M, int K, int Nc, const float* __restrict__ pos) {
  __shared__ ushort_t As[2][128 * LDST];
  __shared__ ushort_t Bs[2][128 * LDST];
  int tid = threadIdx.x;
  int wave = tid >> 6, lane = tid & 63;
  int wr = (wave >> 1) * 64, wc = (wave & 1) * 64;
  int q = lane >> 4, l15 = lane & 15;
  int m0 = blockIdx.x * 128, n0 = blockIdx.y * 128;
  int kbeg = (KP > 1) ? blockIdx.z * (K / KP) : 0;
  int kend = kbeg + K / KP;

  floatx4 acc[4][4];
#pragma unroll
  for (int i = 0; i < 4; ++i)
#pragma unroll
    for (int j = 0; j < 4; ++j)
#pragma unroll
      for (int e = 0; e < 4; ++e) acc[i][j][e] = 0.f;

  int sr = tid >> 2;
  int kq = tid & 3;

  for (int k0 = kbeg; k0 < kend; k0 += 32) {
#pragma unroll
    for (int it = 0; it < 2; ++it) {
      int rr = it * 64 + sr;
      int gm = m0 + rr;
      if (gm > M - 1) gm = M - 1;
      size_t aoff = (size_t)gm * K + k0 + kq * 8;
      *(uint4*)&As[0][rr * LDST + kq * 8] = *(const uint4*)&Ahi[aoff];
      *(uint4*)&As[1][rr * LDST + kq * 8] = *(const uint4*)&Alo[aoff];
      size_t boff = (size_t)(n0 + rr) * K + k0 + kq * 8;
      *(uint4*)&Bs[0][rr * LDST + kq * 8] = *(const uint4*)&Bhi[boff];
      *(uint4*)&Bs[1][rr * LDST + kq * 8] = *(const uint4*)&Blo[boff];
    }
    __syncthreads();
    short8x ah[4], al[4], bh[4], bl[4];
    int abase = (wr + l15) * LDST + q * 8;
    int bbase = (wc + l15) * LDST + q * 8;
#pragma unroll
    for (int i = 0; i < 4; ++i) {
      ah[i] = *(const short8x*)&As[0][abase + i * 16 * LDST];
      al[i] = *(const short8x*)&As[1][abase + i * 16 * LDST];
      bh[i] = *(const short8x*)&Bs[0][bbase + i * 16 * LDST];
      bl[i] = *(const short8x*)&Bs[1][bbase + i * 16 * LDST];
    }
#pragma unroll
    for (int i = 0; i < 4; ++i)
#pragma unroll
      for (int j = 0; j < 4; ++j) {
        acc[i][j] = __builtin_amdgcn_mfma_f32_16x16x32_bf16(ah[i], bh[j], acc[i][j], 0, 0, 0);
        acc[i][j] = __builtin_amdgcn_mfma_f32_16x16x32_bf16(ah[i], bl[j], acc[i][j], 0, 0, 0);
        acc[i][j] = __builtin_amdgcn_mfma_f32_16x16x32_bf16(al[i], bh[j], acc[i][j], 0, 0, 0);
      }
    __syncthreads();
  }

#pragma unroll
  for (int i = 0; i < 4; ++i) {
#pragma unroll
    for (int j = 0; j < 4; ++j) {
      int col = n0 + wc + j * 16 + l15;
#pragma unroll
      for (int r4 = 0; r4 < 4; ++r4) {
        int gr = m0 + wr + i * 16 + q * 4 + r4;
        if (gr >= M) continue;
        if (EPI == EPI_ATOM) {
          float v = acc[i][j][r4];
          if (KP == 1 || blockIdx.z == 0) v += bias[col];
          unsafeAtomicAdd(&Cf[(size_t)gr * 768 + col], v);
        } else {
          float v = acc[i][j][r4] + bias[col];
          if (EPI == EPI_PATCH) {
            int n = gr / 196, t = gr - n * 196 + 1;
            Cf[((size_t)n * S_ + t) * 768 + col] = v + pos[(size_t)t * 768 + col];
          } else {  // EPI_GELU
            float g = 0.5f * v * (1.f + erff(v * 0.70710678118654752f));
            ushort_t hi = f2bf_rn(g);
            size_t o = (size_t)gr * FF_ + col;
            Chi[o] = hi;
            Clo[o] = f2bf_rn(g - bf2f(hi));
          }
        }
      }
    }
  }
}

// ---------------- LayerNorm -> bf16 hi/lo ----------------
__global__ __launch_bounds__(256) void ln_kernel(const float* __restrict__ x,
                                                 ushort_t* __restrict__ hhi,
                                                 ushort_t* __restrict__ hlo,
                                                 const float* __restrict__ w,
                                                 const float* __restrict__ b) {
  int tok = blockIdx.x * 4 + (threadIdx.x >> 6);
  int lane = threadIdx.x & 63;
  const float* xr = x + (size_t)tok * 768;
  float4 v[3];
  float s = 0.f, s2 = 0.f;
#pragma unroll
  for (int i = 0; i < 3; ++i) {
    v[i] = *(const float4*)&xr[i * 256 + lane * 4];
    s += v[i].x + v[i].y + v[i].z + v[i].w;
    s2 += v[i].x * v[i].x + v[i].y * v[i].y + v[i].z * v[i].z + v[i].w * v[i].w;
  }
#pragma unroll
  for (int m = 32; m > 0; m >>= 1) { s += __shfl_xor(s, m, 64); s2 += __shfl_xor(s2, m, 64); }
  float mu = s * (1.f / 768.f);
  float var = s2 * (1.f / 768.f) - mu * mu;
  float rs = rsqrtf(var + 1e-5f);
#pragma unroll
  for (int i = 0; i < 3; ++i) {
    float4 wv = *(const float4*)&w[i * 256 + lane * 4];
    float4 bv = *(const float4*)&b[i * 256 + lane * 4];
    float o0 = (v[i].x - mu) * rs * wv.x + bv.x;
    float o1 = (v[i].y - mu) * rs * wv.y + bv.y;
    float o2 = (v[i].z - mu) * rs * wv.z + bv.z;
    float o3 = (v[i].w - mu) * rs * wv.w + bv.w;
    ushort4 oh, ol;
    oh.x = f2bf_rn(o0); ol.x = f2bf_rn(o0 - bf2f(oh.x));
    oh.y = f2bf_rn(o1); ol.y = f2bf_rn(o1 - bf2f(oh.y));
    oh.z = f2bf_rn(o2); ol.z = f2bf_rn(o2 - bf2f(oh.z));
    oh.w = f2bf_rn(o3); ol.w = f2bf_rn(o3 - bf2f(oh.w));
    size_t o = (size_t)tok * 768 + i * 256 + lane * 4;
    *(ushort4*)&hhi[o] = oh;
    *(ushort4*)&hlo[o] = ol;
  }
}

// ---------------- QKV projection via MFMA: block = 128 tokens x head ----------------
#define KSTR 72

__global__ __launch_bounds__(256) void qkv_mfma(
    const ushort_t* __restrict__ hhi, const ushort_t* __restrict__ hlo,
    const float* __restrict__ Wq, const float* __restrict__ Wk, const float* __restrict__ Wv,
    const float* __restrict__ bq, const float* __restrict__ bk, const float* __restrict__ bv,
    ushort_t* __restrict__ qhi, ushort_t* __restrict__ qlo, ushort_t* __restrict__ khi,
    ushort_t* __restrict__ klo, ushort_t* __restrict__ vhi, ushort_t* __restrict__ vlo) {
  __shared__ ushort_t As[2][128 * KSTR];
  __shared__ ushort_t Ws[2][64 * KSTR];
  int tid = threadIdx.x;
  int wave = tid >> 6, lane = tid & 63;
  int q = lane >> 4, l15 = lane & 15;
  int m0 = blockIdx.x * 128, h = blockIdx.y;
  int wm = wave >> 1, wj = wave & 1;

#pragma unroll
  for (int p = 0; p < 2; ++p) {
    const ushort_t* src = p == 0 ? hhi : hlo;
#pragma unroll
    for (int it = 0; it < 4; ++it) {
      int idx = it * 256 + tid;
      int r = idx >> 3, c = idx & 7;
      int gm = m0 + r;
      if (gm > MTOK - 1) gm = MTOK - 1;
      *(uint4*)&As[p][r * KSTR + c * 8] = *(const uint4*)&src[(size_t)gm * 768 + h * 64 + c * 8];
    }
  }

  const float* Wmat[3] = {Wq + (size_t)h * 4096, Wk + (size_t)h * 4096, Wv + (size_t)h * 4096};
  const float* Bmat[3] = {bq + h * 64, bk + h * 64, bv + h * 64};
  ushort_t* Ohi[3] = {qhi, khi, vhi};
  ushort_t* Olo[3] = {qlo, klo, vlo};

  for (int mat = 0; mat < 3; ++mat) {
    __syncthreads();
#pragma unroll
    for (int it = 0; it < 4; ++it) {
      int idx = it * 256 + tid;
      int r = idx >> 4, c4 = (idx & 15) * 4;
      float4 wv = *(const float4*)&Wmat[mat][r * 64 + c4];
      float vals[4] = {wv.x, wv.y, wv.z, wv.w};
#pragma unroll
      for (int i = 0; i < 4; ++i) {
        ushort_t hi = f2bf_rn(vals[i]);
        Ws[0][(c4 + i) * KSTR + r] = hi;
        Ws[1][(c4 + i) * KSTR + r] = f2bf_rn(vals[i] - bf2f(hi));
      }
    }
    __syncthreads();

    floatx4 acc[4][2];
#pragma unroll
    for (int i = 0; i < 4; ++i)
#pragma unroll
      for (int j = 0; j < 2; ++j)
#pragma unroll
        for (int e = 0; e < 4; ++e) acc[i][j][e] = 0.f;

#pragma unroll
    for (int ks = 0; ks < 2; ++ks) {
      short8x bh[2], bl[2];
#pragma unroll
      for (int j = 0; j < 2; ++j) {
        int bb = (wj * 32 + j * 16 + l15) * KSTR + ks * 32 + q * 8;
        bh[j] = *(const short8x*)&Ws[0][bb];
        bl[j] = *(const short8x*)&Ws[1][bb];
      }
#pragma unroll
      for (int i = 0; i < 4; ++i) {
        int ab = (wm * 64 + i * 16 + l15) * KSTR + ks * 32 + q * 8;
        short8x ah = *(const short8x*)&As[0][ab];
        short8x al = *(const short8x*)&As[1][ab];
#pragma unroll
        for (int j = 0; j < 2; ++j) {
          acc[i][j] = __builtin_amdgcn_mfma_f32_16x16x32_bf16(ah, bh[j], acc[i][j], 0, 0, 0);
          acc[i][j] = __builtin_amdgcn_mfma_f32_16x16x32_bf16(ah, bl[j], acc[i][j], 0, 0, 0);
          acc[i][j] = __builtin_amdgcn_mfma_f32_16x16x32_bf16(al, bh[j], acc[i][j], 0, 0, 0);
        }
      }
    }
#pragma unroll
    for (int i = 0; i < 4; ++i)
#pragma unroll
      for (int j = 0; j < 2; ++j) {
        int col = wj * 32 + j * 16 + l15;
        float bias = Bmat[mat][col];
#pragma unroll
        for (int r = 0; r < 4; ++r) {
          int tok = m0 + wm * 64 + i * 16 + q * 4 + r;
          if (tok >= MTOK) continue;
          float v = acc[i][j][r] + bias;
          ushort_t hi = f2bf_rn(v);
          size_t o = (size_t)tok * 768 + h * 64 + col;
          Ohi[mat][o] = hi;
          Olo[mat][o] = f2bf_rn(v - bf2f(hi));
        }
      }
  }
}

// ---------------- MFMA flash attention ----------------
__global__ __launch_bounds__(256) void attn_mfma(
    const ushort_t* __restrict__ qhi, const ushort_t* __restrict__ qlo,
    const ushort_t* __restrict__ khi, const ushort_t* __restrict__ klo,
    const ushort_t* __restrict__ vhi, const ushort_t* __restrict__ vlo,
    float* __restrict__ X) {
  __shared__ ushort_t Qs[2][64 * KSTR];
  __shared__ ushort_t Ks[2][64 * KSTR];
  __shared__ ushort_t Vs[2][64 * KSTR];
  int tid = threadIdx.x;
  int wave = tid >> 6, lane = tid & 63;
  int q = lane >> 4, l15 = lane & 15;
  int qc = blockIdx.x, h = blockIdx.y, n = blockIdx.z;
  int q0 = qc * 64;
  int row0 = wave * 16;

#pragma unroll
  for (int p = 0; p < 2; ++p) {
    const ushort_t* src = p == 0 ? qhi : qlo;
#pragma unroll
    for (int it = 0; it < 2; ++it) {
      int idx = it * 256 + tid;
      int r = idx >> 3, c = idx & 7;
      int gr = q0 + r;
      if (gr > S_ - 1) gr = S_ - 1;
      *(uint4*)&Qs[p][r * KSTR + c * 8] =
          *(const uint4*)&src[((size_t)n * S_ + gr) * 768 + h * 64 + c * 8];
    }
  }
  __syncthreads();
  short8x qa_h[2], qa_l[2];
#pragma unroll
  for (int ks = 0; ks < 2; ++ks) {
    int ab = (row0 + l15) * KSTR + ks * 32 + q * 8;
    qa_h[ks] = *(const short8x*)&Qs[0][ab];
    qa_l[ks] = *(const short8x*)&Qs[1][ab];
  }

  float mrow[4], lrow[4];
  floatx4 oa[4];
#pragma unroll
  for (int r = 0; r < 4; ++r) { mrow[r] = -INFINITY; lrow[r] = 0.f; }
#pragma unroll
  for (int j = 0; j < 4; ++j)
#pragma unroll
    for (int e = 0; e < 4; ++e) oa[j][e] = 0.f;

  for (int t = 0; t < 4; ++t) {
    __syncthreads();
#pragma unroll
    for (int p = 0; p < 2; ++p) {
      const ushort_t* src = p == 0 ? khi : klo;
#pragma unroll
      for (int it = 0; it < 2; ++it) {
        int idx = it * 256 + tid;
        int r = idx >> 3, c = idx & 7;
        int gk = t * 64 + r;
        if (gk > S_ - 1) gk = S_ - 1;
        *(uint4*)&Ks[p][r * KSTR + c * 8] =
            *(const uint4*)&src[((size_t)n * S_ + gk) * 768 + h * 64 + c * 8];
      }
    }
    {
      int d = tid & 63, kg = tid >> 6;
#pragma unroll
      for (int p = 0; p < 2; ++p) {
        const ushort_t* src = p == 0 ? vhi : vlo;
#pragma unroll
        for (int k4 = 0; k4 < 4; ++k4) {
          ushort4 pk;
          ushort_t tmp[4];
#pragma unroll
          for (int i = 0; i < 4; ++i) {
            int gk = t * 64 + kg * 16 + k4 * 4 + i;
            if (gk > S_ - 1) gk = S_ - 1;
            tmp[i] = src[((size_t)n * S_ + gk) * 768 + h * 64 + d];
          }
          pk.x = tmp[0]; pk.y = tmp[1]; pk.z = tmp[2]; pk.w = tmp[3];
          *(ushort4*)&Vs[p][d * KSTR + kg * 16 + k4 * 4] = pk;
        }
      }
    }
    __syncthreads();

    floatx4 sc[4];
#pragma unroll
    for (int j = 0; j < 4; ++j) {
#pragma unroll
      for (int e = 0; e < 4; ++e) sc[j][e] = 0.f;
#pragma unroll
      for (int ks = 0; ks < 2; ++ks) {
        int bb = (j * 16 + l15) * KSTR + ks * 32 + q * 8;
        short8x kb_h = *(const short8x*)&Ks[0][bb];
        short8x kb_l = *(const short8x*)&Ks[1][bb];
        sc[j] = __builtin_amdgcn_mfma_f32_16x16x32_bf16(qa_h[ks], kb_h, sc[j], 0, 0, 0);
        sc[j] = __builtin_amdgcn_mfma_f32_16x16x32_bf16(qa_h[ks], kb_l, sc[j], 0, 0, 0);
        sc[j] = __builtin_amdgcn_mfma_f32_16x16x32_bf16(qa_l[ks], kb_h, sc[j], 0, 0, 0);
      }
    }
    __syncthreads();

    bool kvalid[4];
#pragma unroll
    for (int j = 0; j < 4; ++j) kvalid[j] = (t * 64 + j * 16 + l15) < S_;
#pragma unroll
    for (int r = 0; r < 4; ++r) {
      float sv[4];
#pragma unroll
      for (int j = 0; j < 4; ++j) sv[j] = kvalid[j] ? sc[j][r] * 0.125f : -INFINITY;
      float mx = fmaxf(fmaxf(sv[0], sv[1]), fmaxf(sv[2], sv[3]));
#pragma unroll
      for (int msk = 1; msk < 16; msk <<= 1) mx = fmaxf(mx, __shfl_xor(mx, msk, 64));
      float mn = fmaxf(mrow[r], mx);
      float al = expf(mrow[r] - mn);
      float p[4], ps = 0.f;
#pragma unroll
      for (int j = 0; j < 4; ++j) { p[j] = expf(sv[j] - mn); ps += p[j]; }
#pragma unroll
      for (int msk = 1; msk < 16; msk <<= 1) ps += __shfl_xor(ps, msk, 64);
      lrow[r] = lrow[r] * al + ps;
      mrow[r] = mn;
#pragma unroll
      for (int j = 0; j < 4; ++j) oa[j][r] *= al;
      int prow = (row0 + q * 4 + r) * KSTR;
#pragma unroll
      for (int j = 0; j < 4; ++j) {
        ushort_t phv = f2bf_rn(p[j]);
        Ks[0][prow + j * 16 + l15] = phv;
        Ks[1][prow + j * 16 + l15] = f2bf_rn(p[j] - bf2f(phv));
      }
    }

#pragma unroll
    for (int ks = 0; ks < 2; ++ks) {
      int ab = (row0 + l15) * KSTR + ks * 32 + q * 8;
      short8x pa_h = *(const short8x*)&Ks[0][ab];
      short8x pa_l = *(const short8x*)&Ks[1][ab];
#pragma unroll
      for (int j = 0; j < 4; ++j) {
        int bb = (j * 16 + l15) * KSTR + ks * 32 + q * 8;
        short8x vb_h = *(const short8x*)&Vs[0][bb];
        short8x vb_l = *(const short8x*)&Vs[1][bb];
        oa[j] = __builtin_amdgcn_mfma_f32_16x16x32_bf16(pa_h, vb_h, oa[j], 0, 0, 0);
        oa[j] = __builtin_amdgcn_mfma_f32_16x16x32_bf16(pa_h, vb_l, oa[j], 0, 0, 0);
        oa[j] = __builtin_amdgcn_mfma_f32_16x16x32_bf16(pa_l, vb_h, oa[j], 0, 0, 0);
      }
    }
  }

#pragma unroll
  for (int r = 0; r < 4; ++r) {
    int row = q0 + row0 + q * 4 + r;
    if (row >= S_) continue;
    float invl = 1.f / lrow[r];
#pragma unroll
    for (int j = 0; j < 4; ++j)
      X[((size_t)n * S_ + row) * 768 + h * 64 + j * 16 + l15] += oa[j][r] * invl;
  }
}

// ---------------- classifier head + softmax ----------------
__global__ __launch_bounds__(256) void head_kernel(const float* __restrict__ x,
                                                   const float* __restrict__ Wout,
                                                   const float* __restrict__ bout,
                                                   float* __restrict__ out) {
  __shared__ float cls[768];
  __shared__ float red[4];
  int n = blockIdx.x, tid = threadIdx.x;
  int w = tid >> 6, lane = tid & 63;
  for (int d = tid; d < 768; d += 256) cls[d] = x[(size_t)n * S_ * D_ + d];
  __syncthreads();
  int j0 = tid * 4;
  bool act = j0 < 1000;
  float a0 = 0.f, a1 = 0.f, a2 = 0.f, a3 = 0.f;
  if (act) {
    for (int kk = 0; kk < 768; ++kk) {
      float c = cls[kk];
      float4 wv = *(const float4*)&Wout[(size_t)kk * 1000 + j0];
      a0 += c * wv.x;
      a1 += c * wv.y;
      a2 += c * wv.z;
      a3 += c * wv.w;
    }
    a0 += bout[j0];
    a1 += bout[j0 + 1];
    a2 += bout[j0 + 2];
    a3 += bout[j0 + 3];
  }
  float mx = act ? fmaxf(fmaxf(a0, a1), fmaxf(a2, a3)) : -INFINITY;
#pragma unroll
  for (int m = 32; m > 0; m >>= 1) mx = fmaxf(mx, __shfl_xor(mx, m, 64));
  if (lane == 0) red[w] = mx;
  __syncthreads();
  mx = fmaxf(fmaxf(red[0], red[1]), fmaxf(red[2], red[3]));
  __syncthreads();
  float e0 = 0.f, e1 = 0.f, e2 = 0.f, e3 = 0.f, ss = 0.f;
  if (act) {
    e0 = expf(a0 - mx);
    e1 = expf(a1 - mx);
    e2 = expf(a2 - mx);
    e3 = expf(a3 - mx);
    ss = e0 + e1 + e2 + e3;
  }
#pragma unroll
  for (int m = 32; m > 0; m >>= 1) ss += __shfl_xor(ss, m, 64);
  if (lane == 0) red[w] = ss;
  __syncthreads();
  ss = red[0] + red[1] + red[2] + red[3];
  if (act) {
    float inv = 1.f / ss;
    out[(size_t)n * 1000 + j0] = e0 * inv;
    out[(size_t)n * 1000 + j0 + 1] = e1 * inv;
    out[(size_t)n * 1000 + j0 + 2] = e2 * inv;
    out[(size_t)n * 1000 + j0 + 3] = e3 * inv;
  }
}

extern "C" void kernel_launch(void* const* d_in, const int* in_sizes, int n_in, void* d_out,
                              int out_size, void* d_ws, size_t ws_size, hipStream_t stream) {
  const float* images = (const float*)d_in[0];
  const float* Wm = (const float*)d_in[1];
  const float* bm = (const float*)d_in[2];
  const float* cls_tok = (const float*)d_in[3];
  const float* pos_emb = (const float*)d_in[4];
  const float* ln1_w = (const float*)d_in[5];
  const float* ln1_b = (const float*)d_in[6];
  const float* Wq = (const float*)d_in[7];
  const float* bq = (const float*)d_in[8];
  const float* Wk = (const float*)d_in[9];
  const float* bk = (const float*)d_in[10];
  const float* Wv = (const float*)d_in[11];
  const float* bv = (const float*)d_in[12];
  const float* ln2_w = (const float*)d_in[13];
  const float* ln2_b = (const float*)d_in[14];
  const float* W1 = (const float*)d_in[15];
  const float* b1 = (const float*)d_in[16];
  const float* W2 = (const float*)d_in[17];
  const float* b2 = (const float*)d_in[18];
  const float* Wout = (const float*)d_in[19];
  const float* bout = (const float*)d_in[20];
  float* out = (float*)d_out;

  // --- workspace map (identical to round-3 layout, which fits) ---
  // [0, 19.4M)        x            ND fp32
  // [19.4M, 38.7M)    hhi/hlo      2 × ND bf16
  // R = [38.7M, ...)  overlay:
  //   q/k/v hi+lo planes  6 × ND bf16 = 58.1 MB   (attn phase)
  //   ghi/glo             2 × MTOK*FF bf16 = 77.4 MB (MLP phase)
  //   patches hi/lo       (pre-layer phase)
  //   WB = R + 77.4 MB: w1hi/w1lo/w2hi/w2lo  4 × 768*FF bf16 = 18.9 MB
  char* base = (char*)d_ws;
  float* x = (float*)base;
  ushort_t* hhi = (ushort_t*)(base + (size_t)ND * 4);
  ushort_t* hlo = hhi + (size_t)ND;
  char* R = base + (size_t)ND * 8;
  ushort_t* qhi = (ushort_t*)R;
  ushort_t* qlo = qhi + (size_t)ND;
  ushort_t* khi = qlo + (size_t)ND;
  ushort_t* klo = khi + (size_t)ND;
  ushort_t* vhi = klo + (size_t)ND;
  ushort_t* vlo = vhi + (size_t)ND;
  ushort_t* ghi = (ushort_t*)R;
  ushort_t* glo = ghi + (size_t)MTOK * FF_;
  ushort_t* phi = (ushort_t*)R;
  ushort_t* plo = phi + (size_t)6272 * 768;
  char* WB = R + (size_t)MTOK * FF_ * 4;
  ushort_t* w1hi = (ushort_t*)WB;
  ushort_t* w1lo = w1hi + (size_t)768 * FF_;
  ushort_t* w2hi = w1lo + (size_t)768 * FF_;
  ushort_t* w2lo = w2hi + (size_t)768 * FF_;

  patchify_kernel<<<(6272 * 768 + 255) / 256, 256, 0, stream>>>(images, phi, plo);
  wconvert_kernel<<<dim3(24, 24), 256, 0, stream>>>(Wm, w1hi, w1lo, 768, 768);
  gemm_mfma<EPI_PATCH, 1><<<dim3(49, 6), 256, 0, stream>>>(phi, plo, w1hi, w1lo, bm, x,
                                                           nullptr, nullptr, 6272, 768, 768,
                                                           pos_emb);
  cls_init_kernel<<<(32 * 768) / 256, 256, 0, stream>>>(cls_tok, pos_emb, x);

  for (int l = 0; l < 8; ++l) {
    ln_kernel<<<MTOK / 4, 256, 0, stream>>>(x, hhi, hlo, ln1_w + l * 768, ln1_b + l * 768);
    qkv_mfma<<<dim3(50, 12), 256, 0, stream>>>(
        hhi, hlo, Wq + (size_t)l * 49152, Wk + (size_t)l * 49152, Wv + (size_t)l * 49152,
        bq + l * 768, bk + l * 768, bv + l * 768, qhi, qlo, khi, klo, vhi, vlo);
    attn_mfma<<<dim3(4, 12, 32), 256, 0, stream>>>(qhi, qlo, khi, klo, vhi, vlo, x);
    ln_kernel<<<MTOK / 4, 256, 0, stream>>>(x, hhi, hlo, ln2_w + l * 768, ln2_b + l * 768);
    wconvert_kernel<<<dim3(96, 24), 256, 0, stream>>>(W1 + (size_t)l * 768 * FF_, w1hi, w1lo,
                                                      768, FF_);
    gemm_mfma<EPI_GELU, 1><<<dim3(50, 24), 256, 0, stream>>>(hhi, hlo, w1hi, w1lo, b1 + l * FF_,
                                                             nullptr, ghi, glo, MTOK, 768, FF_,
                                                             nullptr);
    wconvert_kernel<<<dim3(24, 96), 256, 0, stream>>>(W2 + (size_t)l * FF_ * 768, w2hi, w2lo,
                                                      FF_, 768);
    // FC2 split-K=2: both halves atomically accumulate into x (z==0 adds bias)
    gemm_mfma<EPI_ATOM, 2><<<dim3(50, 6, 2), 256, 0, stream>>>(ghi, glo, w2hi, w2lo,
                                                               b2 + l * 768, x, nullptr,
                                                               nullptr, MTOK, FF_, 768,
                                                               nullptr);
  }
  head_kernel<<<32, 256, 0, stream>>>(x, Wout, bout, out);
}